// Round 2
// baseline (352.875 us; speedup 1.0000x reference)
//
#include <hip/hip_runtime.h>
#include <hip/hip_bf16.h>
#include <math.h>

// Problem constants (fixed by the reference)
constexpr int T_LEN = 2048;
constexpr int B_SZ  = 2;
constexpr int D_DIM = 768;
constexpr int H_NUM = 8;
constexpr int HD    = 96;        // D/H
constexpr int FFN   = 3072;
constexpr float EPS = 1e-5f;
constexpr int TB    = T_LEN * B_SZ;   // 4096 rows
constexpr int QKV_LD = 3 * D_DIM;     // 2304
constexpr int NSPLIT = 4;             // attention split-K factor
constexpr int CHUNK  = T_LEN / NSPLIT;   // 512 keys per block
// (1/sqrt(96)) * log2(e): folded into wq/bq so softmax is a bare v_exp (2^x)
constexpr float SC_LOG2E = 0.14724444458547f;

typedef __attribute__((ext_vector_type(8)))  short short8;
typedef __attribute__((ext_vector_type(4)))  short short4v;
typedef __attribute__((ext_vector_type(4)))  float f32x4;
typedef __attribute__((ext_vector_type(16))) float f32x16;

__device__ __forceinline__ short f2bf(float f) {
    union { float f; unsigned u; } v; v.f = f;
    return (short)((v.u + 0x7FFFu + ((v.u >> 16) & 1u)) >> 16);   // RNE
}
__device__ __forceinline__ float bf2f(short s) {
    union { unsigned u; float f; } v;
    v.u = ((unsigned)(unsigned short)s) << 16;
    return v.f;
}
// packed f32x2 -> bf16x2 (V_CVT_PK_BF16_F32 on gfx950); a in low half
__device__ __forceinline__ unsigned pkbf(float a, float b) {
    union { __hip_bfloat162 h; unsigned u; } v;
    v.h = __float22bfloat162_rn(make_float2(a, b));
    return v.u;
}

// async global->LDS, 16B per lane; LDS dst = wave-uniform base + lane*16
__device__ __forceinline__ void async_ld16(const short* g, short* l) {
    __builtin_amdgcn_global_load_lds(
        (const __attribute__((address_space(1))) unsigned int*)g,
        (__attribute__((address_space(3))) unsigned int*)l, 16, 0, 0);
}

// ---------------------------------------------------------------------------
// Prep: fused fp32 -> bf16 conversion over 7 segments (x + 6 weight blobs),
// with a per-segment scale (wq is pre-scaled by SC_LOG2E so attention's
// softmax exp becomes a bare v_exp_f32).
// ---------------------------------------------------------------------------
struct CvtArgs {
    const float* src[7];
    short*       dst[7];
    float        scl[7];
    int          end4[7];   // cumulative segment ends, in float4 units
};

__global__ __launch_bounds__(256)
void cvt_all(CvtArgs a, int total4) {
    const int i = blockIdx.x * 256 + threadIdx.x;
    if (i >= total4) return;
    int s = 0;
    while (i >= a.end4[s]) ++s;
    const int base = s ? a.end4[s - 1] : 0;
    const int j = i - base;
    const float sc = a.scl[s];
    const float4 v = ((const float4*)a.src[s])[j];
    short4v o;
    o[0] = f2bf(v.x * sc); o[1] = f2bf(v.y * sc);
    o[2] = f2bf(v.z * sc); o[3] = f2bf(v.w * sc);
    *(short4v*)(a.dst[s] + (size_t)j * 4) = o;
}

__global__ __launch_bounds__(256)
void concat_bias(const float* __restrict__ bq, const float* __restrict__ bk,
                 const float* __restrict__ bv, float* __restrict__ dst) {
    const int i = blockIdx.x * 256 + threadIdx.x;
    if (i >= QKV_LD) return;
    dst[i] = (i < 768) ? bq[i] * SC_LOG2E : (i < 1536 ? bk[i - 768] : bv[i - 1536]);
}

// ---------------------------------------------------------------------------
// bf16 MFMA GEMM: C[M,N] = A[M,K] @ W[N,K]^T + bias[N]  (optional ReLU)
// 128(M) x BN tile, BK=32, 256 threads = 4 waves.
// R2: 2-phase double-buffered pipeline (T3-minimum): stage tile t+1 into
// buf^1 while computing tile t from buf; ONE __syncthreads per K-step
// (its vmcnt(0)+lgkmcnt(0) drain covers both hazards). Load latency now
// overlaps MFMA instead of serializing before it.
// ---------------------------------------------------------------------------
template <int BN, typename OutT, bool RELU>
__global__ __launch_bounds__(256)
void gemm_mfma(const short* __restrict__ A, const short* __restrict__ W,
               const float* __restrict__ bias, OutT* __restrict__ C,
               int M, int N, int K) {
    constexpr int NI = BN / 32;   // 16-col tiles per wave
    __shared__ __align__(16) short As[2][128 * 32];
    __shared__ __align__(16) short Bs[2][BN * 32];

    const int tid  = threadIdx.x;
    const int w    = tid >> 6;
    const int lane = tid & 63;
    const int l16  = lane & 15;
    const int q4   = lane >> 4;          // 0..3
    const int row0 = blockIdx.y * 128;
    const int col0 = blockIdx.x * BN;
    const int wm   = (w >> 1) * 64;      // wave m-offset in tile
    const int wn   = (w & 1) * (BN / 2); // wave n-offset in tile

    const short* gA0 = A + (size_t)(row0 + (tid >> 2)) * K + (tid & 3) * 8;
    const short* gA1 = gA0 + (size_t)64 * K;
    const short* gB0 = W + (size_t)(col0 + (tid >> 2)) * K + (tid & 3) * 8;
    const short* gB1 = gB0 + (size_t)64 * K;

    f32x4 acc[4][NI];
#pragma unroll
    for (int mi = 0; mi < 4; ++mi)
#pragma unroll
        for (int ni = 0; ni < NI; ++ni)
#pragma unroll
            for (int r = 0; r < 4; ++r) acc[mi][ni][r] = 0.f;

    // stage next K-tile into buffer `buf`; advances global pointers by 32
    auto stage = [&](int buf) {
        async_ld16(gA0, &As[buf][w * 512]);
        async_ld16(gA1, &As[buf][2048 + w * 512]);
        async_ld16(gB0, &Bs[buf][w * 512]);
        if constexpr (BN == 128) async_ld16(gB1, &Bs[buf][2048 + w * 512]);
        gA0 += 32; gA1 += 32; gB0 += 32;
        if constexpr (BN == 128) gB1 += 32;
    };
    auto compute = [&](int buf) {
        short8 af[4], bfr[NI];
#pragma unroll
        for (int mi = 0; mi < 4; ++mi)
            af[mi] = *(const short8*)&As[buf][(wm + mi * 16 + l16) * 32 + q4 * 8];
#pragma unroll
        for (int ni = 0; ni < NI; ++ni)
            bfr[ni] = *(const short8*)&Bs[buf][(wn + ni * 16 + l16) * 32 + q4 * 8];
#pragma unroll
        for (int mi = 0; mi < 4; ++mi)
#pragma unroll
            for (int ni = 0; ni < NI; ++ni)
                acc[mi][ni] = __builtin_amdgcn_mfma_f32_16x16x32_bf16(
                    af[mi], bfr[ni], acc[mi][ni], 0, 0, 0);
    };

    // prologue: tile 0 into buf0
    stage(0);
    __syncthreads();
    // steady state: 2 K-steps per double-iteration (K/32 is even for all
    // call sites: 768/32=24, 3072/32=96)
    for (int k0 = 0; k0 < K; k0 += 64) {
        stage(1);              // tile t+1 in flight during compute(t)
        compute(0);
        __syncthreads();       // drains vmcnt(0): buf1 ready; lgkm: buf0 reads done
        if (k0 + 64 < K) stage(0);
        compute(1);
        __syncthreads();
    }

    float bcol[NI];
#pragma unroll
    for (int ni = 0; ni < NI; ++ni) bcol[ni] = bias[col0 + wn + ni * 16 + l16];
#pragma unroll
    for (int mi = 0; mi < 4; ++mi) {
#pragma unroll
        for (int r = 0; r < 4; ++r) {
            const int row = row0 + wm + mi * 16 + q4 * 4 + r;
#pragma unroll
            for (int ni = 0; ni < NI; ++ni) {
                float v = acc[mi][ni][r] + bcol[ni];
                if (RELU) v = fmaxf(v, 0.f);
                const int col = col0 + wn + ni * 16 + l16;
                if constexpr (sizeof(OutT) == 2)
                    C[(size_t)row * N + col] = (OutT)f2bf(v);
                else
                    C[(size_t)row * N + col] = v;
            }
        }
    }
}

// ---------------------------------------------------------------------------
// MFMA bf16 flash attention v4s: split-K + no-max softmax.
// R2: Ks re-laid out [32][112] -> [2][32][56] ([d-half][key][d%48]).
// Old stride 224B = 56 dw: 56*l mod 32 hits only 4 16B slots -> every
// ds_read_b128 of K loaded 16 banks 8x (measured 4.7M conflict cycles).
// New stride 112B = 28 dw: 28*l mod 32 covers all 8 slots -> even bank
// coverage, conflict-free b128, same 7168 B footprint (occupancy kept).
// ---------------------------------------------------------------------------
__global__ __launch_bounds__(128)
void attn_mfma(const short* __restrict__ qkv, short* __restrict__ Opart,
               float* __restrict__ lpart) {
    __shared__ short Ks[2][32][56];  // [d-half][key][d%48] bf16, conflict-free
    __shared__ short Vt[128][44];    // [d][key] bf16, stride 44 (2-way banks)
    __shared__ short Pw[2][32][36];  // per-wave P, stride 36

    const int tid  = threadIdx.x;
    const int w    = tid >> 6;
    const int lane = tid & 63;
    const int l31  = lane & 31;
    const int h5   = lane >> 5;
    const int t0   = blockIdx.x * 64;
    const int bh   = blockIdx.y;
    const int split = blockIdx.z;
    const int b    = bh >> 3;
    const int h    = bh & 7;

    // Vt rows 96..127: row 96 = ones (denominator column), rest zero
    for (int i = tid; i < 32 * 44; i += 128) {
        const int rr = i / 44, cc = i % 44;
        Vt[96 + rr][cc] = (rr == 0 && cc < 32) ? (short)0x3F80 : (short)0;
    }

    // Q fragments straight from global bf16 (wave-private 32 q-rows)
    short8 qf[6];
    {
        const int qrow = t0 + w * 32 + l31;
        const short* qb = qkv + ((size_t)qrow * B_SZ + b) * QKV_LD + h * HD;
#pragma unroll
        for (int ks = 0; ks < 6; ++ks)
            qf[ks] = *(const short8*)&qb[ks * 16 + h5 * 8];
    }

    // --- staging assignments (wave-specialized), chunk-local keys ---
    const int k_row = lane >> 1;                  // wave 0: key row
    const int k_half = lane & 1;                  // wave 0: d-half (0: d<48)
    const short* gK = qkv + ((size_t)(split * CHUNK + k_row) * B_SZ + b) * QKV_LD
                      + D_DIM + h * HD + k_half * 48;
    const int dg = (lane & 7) * 12;               // wave 1: d-group
    const int kg = (lane >> 3) * 4;               // wave 1: key-group
    const short* gV = qkv + ((size_t)(split * CHUNK + kg) * B_SZ + b) * QKV_LD
                      + 2 * D_DIM + h * HD + dg;
    const size_t step  = (size_t)32 * B_SZ * QKV_LD;
    const size_t vrow  = (size_t)B_SZ * QKV_LD;   // one key row

    f32x16 oacc[4];
#pragma unroll
    for (int nt = 0; nt < 4; ++nt)
#pragma unroll
        for (int r = 0; r < 16; ++r) oacc[nt][r] = 0.f;

    // prefetch tile 0 (wave-specialized, registers)
    short8  kpf[6];
    short4v vpf[4][3];
    if (w == 0) {
#pragma unroll
        for (int j = 0; j < 6; ++j) kpf[j] = *(const short8*)(gK + j * 8);
    } else {
#pragma unroll
        for (int r = 0; r < 4; ++r)
#pragma unroll
            for (int c = 0; c < 3; ++c)
                vpf[r][c] = *(const short4v*)(gV + r * vrow + c * 4);
    }

    for (int it = 0; it < CHUNK / 32; ++it) {
        __syncthreads();   // previous tile fully consumed by both waves
        if (w == 0) {
#pragma unroll
            for (int j = 0; j < 6; ++j)
                *(short8*)&Ks[k_half][k_row][j * 8] = kpf[j];
        } else {
#pragma unroll
            for (int d = 0; d < 12; ++d) {
                short4v t;
                t[0] = vpf[0][d >> 2][d & 3];
                t[1] = vpf[1][d >> 2][d & 3];
                t[2] = vpf[2][d >> 2][d & 3];
                t[3] = vpf[3][d >> 2][d & 3];
                *(short4v*)&Vt[dg + d][kg] = t;
            }
        }
        __syncthreads();

        // prefetch next tile (latency hides behind this tile's compute)
        if (it + 1 < CHUNK / 32) {
            const size_t off = (size_t)(it + 1) * step;
            if (w == 0) {
#pragma unroll
                for (int j = 0; j < 6; ++j)
                    kpf[j] = *(const short8*)(gK + off + j * 8);
            } else {
#pragma unroll
                for (int r = 0; r < 4; ++r)
#pragma unroll
                    for (int c = 0; c < 3; ++c)
                        vpf[r][c] = *(const short4v*)(gV + off + r * vrow + c * 4);
            }
        }

        // S = Q.K^T  (Q pre-scaled by scale*log2e)
        f32x16 sa;
#pragma unroll
        for (int r = 0; r < 16; ++r) sa[r] = 0.f;
#pragma unroll
        for (int ks = 0; ks < 6; ++ks) {
            const int half = ks / 3;                   // compile-time per ks
            const int base = ks * 16 - half * 48;      // local d within half
            const short8 kf = *(const short8*)&Ks[half][l31][base + h5 * 8];
            sa = __builtin_amdgcn_mfma_f32_32x32x16_bf16(qf[ks], kf, sa, 0, 0, 0);
        }

        // P = 2^S (bare v_exp); packed cvt to bf16; C-layout -> LDS -> A-layout
        float pvx[16];
#pragma unroll
        for (int r = 0; r < 16; ++r) pvx[r] = __builtin_amdgcn_exp2f(sa[r]);
#pragma unroll
        for (int rp = 0; rp < 8; ++rp) {
            const unsigned u = pkbf(pvx[2 * rp], pvx[2 * rp + 1]);
            const int row = ((2 * rp) & 3) + 8 * ((2 * rp) >> 2) + 4 * h5;
            Pw[w][row][l31]     = (short)(u & 0xFFFFu);
            Pw[w][row + 1][l31] = (short)(u >> 16);
        }

        // O += P.V  (+ denominator column in n-tile 3)
#pragma unroll
        for (int ks2 = 0; ks2 < 2; ++ks2) {
            const short* pp = &Pw[w][l31][ks2 * 16 + h5 * 8];
            const short4v plo = *(const short4v*)pp;
            const short4v phi = *(const short4v*)(pp + 4);
            const short8 pfr = __builtin_shufflevector(plo, phi, 0, 1, 2, 3, 4, 5, 6, 7);
#pragma unroll
            for (int nt = 0; nt < 4; ++nt) {
                const short* vp = &Vt[nt * 32 + l31][ks2 * 16 + h5 * 8];
                const short4v vlo = *(const short4v*)vp;
                const short4v vhi = *(const short4v*)(vp + 4);
                const short8 vf = __builtin_shufflevector(vlo, vhi, 0, 1, 2, 3, 4, 5, 6, 7);
                oacc[nt] = __builtin_amdgcn_mfma_f32_32x32x16_bf16(pfr, vf, oacc[nt], 0, 0, 0);
            }
        }
    }

    // epilogue: store UNNORMALIZED O-partial (bf16) + l-partial (f32)
#pragma unroll
    for (int r = 0; r < 16; ++r) {
        const int row  = (r & 3) + 8 * (r >> 2) + 4 * h5;
        const int t    = t0 + w * 32 + row;
        const int grow = t * B_SZ + b;
        short* op = Opart + ((size_t)split * TB + grow) * D_DIM + h * HD;
#pragma unroll
        for (int nt = 0; nt < 3; ++nt)
            op[nt * 32 + l31] = f2bf(oacc[nt][r]);
        if (l31 == 0)
            lpart[((size_t)split * TB + grow) * H_NUM + h] = oacc[3][r];
    }
}

// ---------------------------------------------------------------------------
// Combine: ctx = (sum_c Opart[c]) / (sum_c lpart[c]).  One block per row,
// 192 active lanes x 4 d each, short4 vector loads.
// ---------------------------------------------------------------------------
__global__ __launch_bounds__(256)
void attn_combine(const short* __restrict__ Opart, const float* __restrict__ lpart,
                  short* __restrict__ ctx) {
    const int row = blockIdx.x;
    const int tid = threadIdx.x;
    if (tid >= 192) return;
    const int d = tid * 4;
    const int h = d / 96;
    float o0 = 0.f, o1 = 0.f, o2 = 0.f, o3 = 0.f, l = 0.f;
#pragma unroll
    for (int c = 0; c < NSPLIT; ++c) {
        const short4v v = *(const short4v*)&Opart[((size_t)c * TB + row) * D_DIM + d];
        o0 += bf2f(v[0]); o1 += bf2f(v[1]); o2 += bf2f(v[2]); o3 += bf2f(v[3]);
        l += lpart[((size_t)c * TB + row) * H_NUM + h];
    }
    const float iv = 1.f / l;
    short4v r;
    r[0] = f2bf(o0 * iv); r[1] = f2bf(o1 * iv);
    r[2] = f2bf(o2 * iv); r[3] = f2bf(o3 * iv);
    *(short4v*)&ctx[(size_t)row * D_DIM + d] = r;
}

// ---------------------------------------------------------------------------
// Fused residual + LayerNorm: out = LN(xres + y)*g + b.  (unchanged)
// ---------------------------------------------------------------------------
template <typename XT, typename OT>
__global__ __launch_bounds__(256)
void ln_residual(const XT* __restrict__ xres, const short* __restrict__ y,
                 const float* __restrict__ g, const float* __restrict__ bb,
                 OT* __restrict__ out) {
    const int row = blockIdx.x;
    const int tid = threadIdx.x;
    const XT*    xr = xres + (size_t)row * D_DIM;
    const short* yr = y + (size_t)row * D_DIM;

    float vals[3];
    float s = 0.f, s2 = 0.f;
#pragma unroll
    for (int i = 0; i < 3; ++i) {
        const int d = tid + i * 256;
        float xv;
        if constexpr (sizeof(XT) == 2) xv = bf2f((short)xr[d]);
        else                           xv = (float)xr[d];
        const float t = xv + bf2f(yr[d]);
        vals[i] = t;
        s += t;
        s2 = fmaf(t, t, s2);
    }
#pragma unroll
    for (int off = 32; off > 0; off >>= 1) {
        s  += __shfl_down(s, off);
        s2 += __shfl_down(s2, off);
    }
    __shared__ float red_s[4], red_s2[4];
    const int wid = tid >> 6, lane = tid & 63;
    if (lane == 0) { red_s[wid] = s; red_s2[wid] = s2; }
    __syncthreads();
    __shared__ float sh_mean, sh_rstd;
    if (tid == 0) {
        const float ts  = red_s[0] + red_s[1] + red_s[2] + red_s[3];
        const float ts2 = red_s2[0] + red_s2[1] + red_s2[2] + red_s2[3];
        const float mean = ts * (1.f / D_DIM);
        const float var  = ts2 * (1.f / D_DIM) - mean * mean;
        sh_mean = mean;
        sh_rstd = rsqrtf(var + EPS);
    }
    __syncthreads();
    const float mean = sh_mean, rstd = sh_rstd;
#pragma unroll
    for (int i = 0; i < 3; ++i) {
        const int d = tid + i * 256;
        const float o = (vals[i] - mean) * rstd * g[d] + bb[d];
        if constexpr (sizeof(OT) == 2)
            out[(size_t)row * D_DIM + d] = (OT)f2bf(o);
        else
            out[(size_t)row * D_DIM + d] = o;
    }
}

// ---------------------------------------------------------------------------
// Launch
// ---------------------------------------------------------------------------
extern "C" void kernel_launch(void* const* d_in, const int* in_sizes, int n_in,
                              void* d_out, int out_size, void* d_ws, size_t ws_size,
                              hipStream_t stream) {
    const float* x     = (const float*)d_in[0];
    const float* wq    = (const float*)d_in[1];
    const float* bq    = (const float*)d_in[2];
    const float* wk    = (const float*)d_in[3];
    const float* bk    = (const float*)d_in[4];
    const float* wv    = (const float*)d_in[5];
    const float* bv    = (const float*)d_in[6];
    const float* wo    = (const float*)d_in[7];
    const float* bo    = (const float*)d_in[8];
    const float* ln1g  = (const float*)d_in[9];
    const float* ln1b  = (const float*)d_in[10];
    const float* w1    = (const float*)d_in[11];
    const float* b1    = (const float*)d_in[12];
    const float* w2    = (const float*)d_in[13];
    const float* b2    = (const float*)d_in[14];
    const float* ln2g  = (const float*)d_in[15];
    const float* ln2b  = (const float*)d_in[16];
    float* out = (float*)d_out;

    // workspace layout (bytes) — total 65,020,928
    char* ws = (char*)d_ws;
    short* qkvb  = (short*)(ws + 0);             // [TB,2304] bf16  0 .. 18,874,368
    short* ctxb  = (short*)(ws + 18874368);      // [TB,768]  bf16  .. 25,165,824
    short* hb    = (short*)(ws + 0);             // [TB,3072] bf16  (reuses qkvb+ctxb)
    short* xb    = (short*)(ws + 25165824);      // [TB,768]  bf16  .. 31,457,280
    short* Opart = (short*)(ws + 25165824);      // 4x[TB,768] bf16 .. 50,331,648 (over xb)
    float* lpart = (float*)(ws + 50331648);      // 4x[TB,8]  f32   .. 50,855,936
    short* tmpb  = (short*)(ws + 25165824);      // [TB,768]  bf16  (over dead Opart)
    short* x1b   = (short*)(ws + 31457280);      // [TB,768]  bf16  (over dead Opart)
    short* wqkv  = (short*)(ws + 50855936);      // [2304,768] bf16 .. 54,394,880
    short* wob   = (short*)(ws + 54394880);      // [768,768]  bf16 .. 55,574,528
    short* w1b   = (short*)(ws + 55574528);      // [3072,768] bf16 .. 60,293,120
    short* w2b   = (short*)(ws + 60293120);      // [768,3072] bf16 .. 65,011,712
    float* bqkv  = (float*)(ws + 65011712);      // [2304] f32      .. 65,020,928

    // fused fp32->bf16 conversions (wq pre-scaled by scale*log2e)
    CvtArgs ca;
    ca.src[0] = x;  ca.dst[0] = xb;   ca.scl[0] = 1.f;
    ca.src[1] = wq; ca.dst[1] = wqkv; ca.scl[1] = SC_LOG2E;
    ca.src[2] = wk; ca.dst[2] = wqkv + 768 * 768;     ca.scl[2] = 1.f;
    ca.src[3] = wv; ca.dst[3] = wqkv + 2 * 768 * 768; ca.scl[3] = 1.f;
    ca.src[4] = wo; ca.dst[4] = wob;  ca.scl[4] = 1.f;
    ca.src[5] = w1; ca.dst[5] = w1b;  ca.scl[5] = 1.f;
    ca.src[6] = w2; ca.dst[6] = w2b;  ca.scl[6] = 1.f;
    const int n4[7] = {TB * D_DIM / 4, 768 * 768 / 4, 768 * 768 / 4, 768 * 768 / 4,
                       768 * 768 / 4, FFN * 768 / 4, 768 * FFN / 4};
    int acc4 = 0;
    for (int i = 0; i < 7; ++i) { acc4 += n4[i]; ca.end4[i] = acc4; }
    cvt_all<<<(acc4 + 255) / 256, 256, 0, stream>>>(ca, acc4);
    concat_bias<<<(QKV_LD + 255) / 256, 256, 0, stream>>>(bq, bk, bv, bqkv);

    // fused QKV projection: [TB,2304] = xb @ wqkv^T + bqkv
    gemm_mfma<128, short, false><<<dim3(QKV_LD / 128, TB / 128), 256, 0, stream>>>(
        xb, wqkv, bqkv, qkvb, TB, QKV_LD, D_DIM);

    // attention (v4s: split-K x4, bare-v_exp softmax, packed P cvt) + combine
    attn_mfma<<<dim3(T_LEN / 64, B_SZ * H_NUM, NSPLIT), dim3(128), 0, stream>>>(
        qkvb, Opart, lpart);
    attn_combine<<<dim3(TB), 256, 0, stream>>>(Opart, lpart, ctxb);

    // out projection (bf16 out) + LN1 (bf16 out)
    gemm_mfma<64, short, false><<<dim3(D_DIM / 64, TB / 128), 256, 0, stream>>>(
        ctxb, wob, bo, tmpb, TB, D_DIM, D_DIM);
    ln_residual<float, short><<<dim3(TB), 256, 0, stream>>>(x, tmpb, ln1g, ln1b, x1b);

    // FFN
    gemm_mfma<128, short, true><<<dim3(FFN / 128, TB / 128), 256, 0, stream>>>(
        x1b, w1b, b1, hb, TB, FFN, D_DIM);
    gemm_mfma<64, short, false><<<dim3(D_DIM / 64, TB / 128), 256, 0, stream>>>(
        hb, w2b, b2, tmpb, TB, D_DIM, FFN);
    ln_residual<short, float><<<dim3(TB), 256, 0, stream>>>(x1b, tmpb, ln2g, ln2b, out);
}

// Round 3
// 320.902 us; speedup vs baseline: 1.0996x; 1.0996x over previous
//
#include <hip/hip_runtime.h>
#include <hip/hip_bf16.h>
#include <math.h>

// Problem constants (fixed by the reference)
constexpr int T_LEN = 2048;
constexpr int B_SZ  = 2;
constexpr int D_DIM = 768;
constexpr int H_NUM = 8;
constexpr int HD    = 96;        // D/H
constexpr int FFN   = 3072;
constexpr float EPS = 1e-5f;
constexpr int TB    = T_LEN * B_SZ;   // 4096 rows
constexpr int QKV_LD = 3 * D_DIM;     // 2304
constexpr int NSPLIT = 4;             // attention split-K factor
constexpr int CHUNK  = T_LEN / NSPLIT;   // 512 keys per block
// (1/sqrt(96)) * log2(e): folded into wq/bq so softmax is a bare v_exp (2^x)
constexpr float SC_LOG2E = 0.14724444458547f;

typedef __attribute__((ext_vector_type(8)))  short short8;
typedef __attribute__((ext_vector_type(4)))  short short4v;
typedef __attribute__((ext_vector_type(2)))  short short2v;
typedef __attribute__((ext_vector_type(4)))  float f32x4;
typedef __attribute__((ext_vector_type(16))) float f32x16;

__device__ __forceinline__ short f2bf(float f) {
    union { float f; unsigned u; } v; v.f = f;
    return (short)((v.u + 0x7FFFu + ((v.u >> 16) & 1u)) >> 16);   // RNE
}
__device__ __forceinline__ float bf2f(short s) {
    union { unsigned u; float f; } v;
    v.u = ((unsigned)(unsigned short)s) << 16;
    return v.f;
}
// packed f32x2 -> bf16x2 (V_CVT_PK_BF16_F32 on gfx950); a in low half
__device__ __forceinline__ unsigned pkbf(float a, float b) {
    union { __hip_bfloat162 h; unsigned u; } v;
    v.h = __float22bfloat162_rn(make_float2(a, b));
    return v.u;
}

// async global->LDS, 16B per lane; LDS dst = wave-uniform base + lane*16
__device__ __forceinline__ void async_ld16(const short* g, short* l) {
    __builtin_amdgcn_global_load_lds(
        (const __attribute__((address_space(1))) unsigned int*)g,
        (__attribute__((address_space(3))) unsigned int*)l, 16, 0, 0);
}

// ---------------------------------------------------------------------------
// Prep: fused fp32 -> bf16 conversion over 7 segments (x + 6 weight blobs),
// with a per-segment scale (wq is pre-scaled by SC_LOG2E so attention's
// softmax exp becomes a bare v_exp_f32).
// ---------------------------------------------------------------------------
struct CvtArgs {
    const float* src[7];
    short*       dst[7];
    float        scl[7];
    int          end4[7];   // cumulative segment ends, in float4 units
};

__global__ __launch_bounds__(256)
void cvt_all(CvtArgs a, int total4) {
    const int i = blockIdx.x * 256 + threadIdx.x;
    if (i >= total4) return;
    int s = 0;
    while (i >= a.end4[s]) ++s;
    const int base = s ? a.end4[s - 1] : 0;
    const int j = i - base;
    const float sc = a.scl[s];
    const float4 v = ((const float4*)a.src[s])[j];
    short4v o;
    o[0] = f2bf(v.x * sc); o[1] = f2bf(v.y * sc);
    o[2] = f2bf(v.z * sc); o[3] = f2bf(v.w * sc);
    *(short4v*)(a.dst[s] + (size_t)j * 4) = o;
}

__global__ __launch_bounds__(256)
void concat_bias(const float* __restrict__ bq, const float* __restrict__ bk,
                 const float* __restrict__ bv, float* __restrict__ dst) {
    const int i = blockIdx.x * 256 + threadIdx.x;
    if (i >= QKV_LD) return;
    dst[i] = (i < 768) ? bq[i] * SC_LOG2E : (i < 1536 ? bk[i - 768] : bv[i - 1536]);
}

// ---------------------------------------------------------------------------
// bf16 MFMA GEMM: C[M,N] = A[M,K] @ W[N,K]^T + bias[N]  (optional ReLU)
// m97-style: 128(M) x BN tile, BK=32, 256 threads = 4 waves.
// R3: reverted to R1 single-buffer structure (R2's explicit dbuf regressed
// -20 us: the barrier drains vmcnt(0) anyway, and 2x LDS cost residency).
// ---------------------------------------------------------------------------
template <int BN, typename OutT, bool RELU>
__global__ __launch_bounds__(256)
void gemm_mfma(const short* __restrict__ A, const short* __restrict__ W,
               const float* __restrict__ bias, OutT* __restrict__ C,
               int M, int N, int K) {
    constexpr int NI = BN / 32;   // 16-col tiles per wave
    __shared__ __align__(16) short As[128 * 32];
    __shared__ __align__(16) short Bs[BN * 32];

    const int tid  = threadIdx.x;
    const int w    = tid >> 6;
    const int lane = tid & 63;
    const int l16  = lane & 15;
    const int q4   = lane >> 4;          // 0..3
    const int row0 = blockIdx.y * 128;
    const int col0 = blockIdx.x * BN;
    const int wm   = (w >> 1) * 64;      // wave m-offset in tile
    const int wn   = (w & 1) * (BN / 2); // wave n-offset in tile

    const short* gA0 = A + (size_t)(row0 + (tid >> 2)) * K + (tid & 3) * 8;
    const short* gA1 = gA0 + (size_t)64 * K;
    const short* gB0 = W + (size_t)(col0 + (tid >> 2)) * K + (tid & 3) * 8;
    const short* gB1 = gB0 + (size_t)64 * K;
    short* ldsA0 = As + w * 512;           // wave-uniform bases
    short* ldsA1 = As + 2048 + w * 512;
    short* ldsB0 = Bs + w * 512;
    short* ldsB1 = Bs + 2048 + w * 512;   // only used when BN==128

    f32x4 acc[4][NI];
#pragma unroll
    for (int mi = 0; mi < 4; ++mi)
#pragma unroll
        for (int ni = 0; ni < NI; ++ni)
#pragma unroll
            for (int r = 0; r < 4; ++r) acc[mi][ni][r] = 0.f;

    for (int k0 = 0; k0 < K; k0 += 32) {
        async_ld16(gA0, ldsA0);
        async_ld16(gA1, ldsA1);
        async_ld16(gB0, ldsB0);
        if constexpr (BN == 128) async_ld16(gB1, ldsB1);
        gA0 += 32; gA1 += 32; gB0 += 32;
        if constexpr (BN == 128) gB1 += 32;
        __syncthreads();   // drain glds

        short8 af[4], bfr[NI];
#pragma unroll
        for (int mi = 0; mi < 4; ++mi)
            af[mi] = *(const short8*)&As[(wm + mi * 16 + l16) * 32 + q4 * 8];
#pragma unroll
        for (int ni = 0; ni < NI; ++ni)
            bfr[ni] = *(const short8*)&Bs[(wn + ni * 16 + l16) * 32 + q4 * 8];
#pragma unroll
        for (int mi = 0; mi < 4; ++mi)
#pragma unroll
            for (int ni = 0; ni < NI; ++ni)
                acc[mi][ni] = __builtin_amdgcn_mfma_f32_16x16x32_bf16(
                    af[mi], bfr[ni], acc[mi][ni], 0, 0, 0);
        __syncthreads();
    }

    float bcol[NI];
#pragma unroll
    for (int ni = 0; ni < NI; ++ni) bcol[ni] = bias[col0 + wn + ni * 16 + l16];
#pragma unroll
    for (int mi = 0; mi < 4; ++mi) {
#pragma unroll
        for (int r = 0; r < 4; ++r) {
            const int row = row0 + wm + mi * 16 + q4 * 4 + r;
#pragma unroll
            for (int ni = 0; ni < NI; ++ni) {
                float v = acc[mi][ni][r] + bcol[ni];
                if (RELU) v = fmaxf(v, 0.f);
                const int col = col0 + wn + ni * 16 + l16;
                if constexpr (sizeof(OutT) == 2)
                    C[(size_t)row * N + col] = (OutT)f2bf(v);
                else
                    C[(size_t)row * N + col] = v;
            }
        }
    }
}

// ---------------------------------------------------------------------------
// MFMA bf16 flash attention v5: split-K + no-max softmax, 4-WAVE blocks.
// R3: 128 q-rows per block (4 waves x 32 rows), grid (T/128, B*H, NSPLIT)
// = 1024 blocks. K/V staging is per-KEY work paid once per block, so
// doubling q-rows halves staging cost per unit of MFMA work:
//   waves 0-1 stage K (3 b128 loads+writes/lane, was 6),
//   waves 2-3 stage V (2-key transpose: 24 extracts + 12 b32 writes/lane,
//   was 4-key: 48 + 12 b64).
// QK/softmax/PV per wave unchanged (own 32 q-rows). R2's conflict-free
// Ks[2][32][56] kept (validated by counter drop; neutral in time).
// ---------------------------------------------------------------------------
__global__ __launch_bounds__(256)
void attn_mfma(const short* __restrict__ qkv, short* __restrict__ Opart,
               float* __restrict__ lpart) {
    __shared__ short Ks[2][32][56];  // [d-half][key][d%48] bf16, conflict-free
    __shared__ short Vt[128][44];    // [d][key] bf16, stride 44
    __shared__ short Pw[4][32][36];  // per-wave P, stride 36

    const int tid  = threadIdx.x;
    const int w    = tid >> 6;
    const int lane = tid & 63;
    const int l31  = lane & 31;
    const int h5   = lane >> 5;
    const int t0   = blockIdx.x * 128;
    const int bh   = blockIdx.y;
    const int split = blockIdx.z;
    const int b    = bh >> 3;
    const int h    = bh & 7;

    // Vt rows 96..127: row 96 = ones (denominator column), rest zero
    for (int i = tid; i < 32 * 44; i += 256) {
        const int rr = i / 44, cc = i % 44;
        Vt[96 + rr][cc] = (rr == 0 && cc < 32) ? (short)0x3F80 : (short)0;
    }

    // Q fragments straight from global bf16 (wave-private 32 q-rows)
    short8 qf[6];
    {
        const int qrow = t0 + w * 32 + l31;
        const short* qb = qkv + ((size_t)qrow * B_SZ + b) * QKV_LD + h * HD;
#pragma unroll
        for (int ks = 0; ks < 6; ++ks)
            qf[ks] = *(const short8*)&qb[ks * 16 + h5 * 8];
    }

    // --- staging assignments (wave-specialized), chunk-local keys ---
    // waves 0,1 (tid 0..127): K. Each (key, quarter) once: 32 keys x 4
    // quarters of 24 d (48 B = 3 short8).
    const int k_row = tid >> 2;                   // 0..31 (valid for tid<128)
    const int k_q   = tid & 3;                    // d-quarter
    const short* gK = qkv + ((size_t)(split * CHUNK + k_row) * B_SZ + b) * QKV_LD
                      + D_DIM + h * HD + k_q * 24;
    // waves 2,3 (ll = tid-128, 0..127): V. 8 d-groups x 16 key-pairs.
    const int ll = tid - 128;
    const int dg = (ll & 7) * 12;                 // d-group
    const int kg = (ll >> 3) * 2;                 // key pair
    const short* gV = qkv + ((size_t)(split * CHUNK + kg) * B_SZ + b) * QKV_LD
                      + 2 * D_DIM + h * HD + dg;
    const size_t step  = (size_t)32 * B_SZ * QKV_LD;
    const size_t vrow  = (size_t)B_SZ * QKV_LD;   // one key row

    f32x16 oacc[4];
#pragma unroll
    for (int nt = 0; nt < 4; ++nt)
#pragma unroll
        for (int r = 0; r < 16; ++r) oacc[nt][r] = 0.f;

    // prefetch tile 0 (wave-specialized, registers)
    short8  kpf[3];
    short4v vpf[2][3];
    if (w < 2) {
#pragma unroll
        for (int j = 0; j < 3; ++j) kpf[j] = *(const short8*)(gK + j * 8);
    } else {
#pragma unroll
        for (int r = 0; r < 2; ++r)
#pragma unroll
            for (int c = 0; c < 3; ++c)
                vpf[r][c] = *(const short4v*)(gV + r * vrow + c * 4);
    }

    for (int it = 0; it < CHUNK / 32; ++it) {
        __syncthreads();   // previous tile fully consumed by all waves
        if (w < 2) {
#pragma unroll
            for (int j = 0; j < 3; ++j)
                *(short8*)&Ks[k_q >> 1][k_row][(k_q & 1) * 24 + j * 8] = kpf[j];
        } else {
#pragma unroll
            for (int d = 0; d < 12; ++d) {
                short2v t;
                t[0] = vpf[0][d >> 2][d & 3];
                t[1] = vpf[1][d >> 2][d & 3];
                *(short2v*)&Vt[dg + d][kg] = t;
            }
        }
        __syncthreads();

        // prefetch next tile (latency hides behind this tile's compute)
        if (it + 1 < CHUNK / 32) {
            const size_t off = (size_t)(it + 1) * step;
            if (w < 2) {
#pragma unroll
                for (int j = 0; j < 3; ++j)
                    kpf[j] = *(const short8*)(gK + off + j * 8);
            } else {
#pragma unroll
                for (int r = 0; r < 2; ++r)
#pragma unroll
                    for (int c = 0; c < 3; ++c)
                        vpf[r][c] = *(const short4v*)(gV + off + r * vrow + c * 4);
            }
        }

        // S = Q.K^T  (Q pre-scaled by scale*log2e)
        f32x16 sa;
#pragma unroll
        for (int r = 0; r < 16; ++r) sa[r] = 0.f;
#pragma unroll
        for (int ks = 0; ks < 6; ++ks) {
            const int half = ks / 3;                   // compile-time per ks
            const int base = ks * 16 - half * 48;      // local d within half
            const short8 kf = *(const short8*)&Ks[half][l31][base + h5 * 8];
            sa = __builtin_amdgcn_mfma_f32_32x32x16_bf16(qf[ks], kf, sa, 0, 0, 0);
        }

        // P = 2^S (bare v_exp); packed cvt to bf16; C-layout -> LDS -> A-layout
        float pvx[16];
#pragma unroll
        for (int r = 0; r < 16; ++r) pvx[r] = __builtin_amdgcn_exp2f(sa[r]);
#pragma unroll
        for (int rp = 0; rp < 8; ++rp) {
            const unsigned u = pkbf(pvx[2 * rp], pvx[2 * rp + 1]);
            const int row = ((2 * rp) & 3) + 8 * ((2 * rp) >> 2) + 4 * h5;
            Pw[w][row][l31]     = (short)(u & 0xFFFFu);
            Pw[w][row + 1][l31] = (short)(u >> 16);
        }

        // O += P.V  (+ denominator column in n-tile 3)
#pragma unroll
        for (int ks2 = 0; ks2 < 2; ++ks2) {
            const short* pp = &Pw[w][l31][ks2 * 16 + h5 * 8];
            const short4v plo = *(const short4v*)pp;
            const short4v phi = *(const short4v*)(pp + 4);
            const short8 pfr = __builtin_shufflevector(plo, phi, 0, 1, 2, 3, 4, 5, 6, 7);
#pragma unroll
            for (int nt = 0; nt < 4; ++nt) {
                const short* vp = &Vt[nt * 32 + l31][ks2 * 16 + h5 * 8];
                const short4v vlo = *(const short4v*)vp;
                const short4v vhi = *(const short4v*)(vp + 4);
                const short8 vf = __builtin_shufflevector(vlo, vhi, 0, 1, 2, 3, 4, 5, 6, 7);
                oacc[nt] = __builtin_amdgcn_mfma_f32_32x32x16_bf16(pfr, vf, oacc[nt], 0, 0, 0);
            }
        }
    }

    // epilogue: store UNNORMALIZED O-partial (bf16) + l-partial (f32)
#pragma unroll
    for (int r = 0; r < 16; ++r) {
        const int row  = (r & 3) + 8 * (r >> 2) + 4 * h5;
        const int t    = t0 + w * 32 + row;
        const int grow = t * B_SZ + b;
        short* op = Opart + ((size_t)split * TB + grow) * D_DIM + h * HD;
#pragma unroll
        for (int nt = 0; nt < 3; ++nt)
            op[nt * 32 + l31] = f2bf(oacc[nt][r]);
        if (l31 == 0)
            lpart[((size_t)split * TB + grow) * H_NUM + h] = oacc[3][r];
    }
}

// ---------------------------------------------------------------------------
// Combine: ctx = (sum_c Opart[c]) / (sum_c lpart[c]).  One block per row,
// 192 active lanes x 4 d each, short4 vector loads.
// ---------------------------------------------------------------------------
__global__ __launch_bounds__(256)
void attn_combine(const short* __restrict__ Opart, const float* __restrict__ lpart,
                  short* __restrict__ ctx) {
    const int row = blockIdx.x;
    const int tid = threadIdx.x;
    if (tid >= 192) return;
    const int d = tid * 4;
    const int h = d / 96;
    float o0 = 0.f, o1 = 0.f, o2 = 0.f, o3 = 0.f, l = 0.f;
#pragma unroll
    for (int c = 0; c < NSPLIT; ++c) {
        const short4v v = *(const short4v*)&Opart[((size_t)c * TB + row) * D_DIM + d];
        o0 += bf2f(v[0]); o1 += bf2f(v[1]); o2 += bf2f(v[2]); o3 += bf2f(v[3]);
        l += lpart[((size_t)c * TB + row) * H_NUM + h];
    }
    const float iv = 1.f / l;
    short4v r;
    r[0] = f2bf(o0 * iv); r[1] = f2bf(o1 * iv);
    r[2] = f2bf(o2 * iv); r[3] = f2bf(o3 * iv);
    *(short4v*)&ctx[(size_t)row * D_DIM + d] = r;
}

// ---------------------------------------------------------------------------
// Fused residual + LayerNorm: out = LN(xres + y)*g + b.  (unchanged)
// ---------------------------------------------------------------------------
template <typename XT, typename OT>
__global__ __launch_bounds__(256)
void ln_residual(const XT* __restrict__ xres, const short* __restrict__ y,
                 const float* __restrict__ g, const float* __restrict__ bb,
                 OT* __restrict__ out) {
    const int row = blockIdx.x;
    const int tid = threadIdx.x;
    const XT*    xr = xres + (size_t)row * D_DIM;
    const short* yr = y + (size_t)row * D_DIM;

    float vals[3];
    float s = 0.f, s2 = 0.f;
#pragma unroll
    for (int i = 0; i < 3; ++i) {
        const int d = tid + i * 256;
        float xv;
        if constexpr (sizeof(XT) == 2) xv = bf2f((short)xr[d]);
        else                           xv = (float)xr[d];
        const float t = xv + bf2f(yr[d]);
        vals[i] = t;
        s += t;
        s2 = fmaf(t, t, s2);
    }
#pragma unroll
    for (int off = 32; off > 0; off >>= 1) {
        s  += __shfl_down(s, off);
        s2 += __shfl_down(s2, off);
    }
    __shared__ float red_s[4], red_s2[4];
    const int wid = tid >> 6, lane = tid & 63;
    if (lane == 0) { red_s[wid] = s; red_s2[wid] = s2; }
    __syncthreads();
    __shared__ float sh_mean, sh_rstd;
    if (tid == 0) {
        const float ts  = red_s[0] + red_s[1] + red_s[2] + red_s[3];
        const float ts2 = red_s2[0] + red_s2[1] + red_s2[2] + red_s2[3];
        const float mean = ts * (1.f / D_DIM);
        const float var  = ts2 * (1.f / D_DIM) - mean * mean;
        sh_mean = mean;
        sh_rstd = rsqrtf(var + EPS);
    }
    __syncthreads();
    const float mean = sh_mean, rstd = sh_rstd;
#pragma unroll
    for (int i = 0; i < 3; ++i) {
        const int d = tid + i * 256;
        const float o = (vals[i] - mean) * rstd * g[d] + bb[d];
        if constexpr (sizeof(OT) == 2)
            out[(size_t)row * D_DIM + d] = (OT)f2bf(o);
        else
            out[(size_t)row * D_DIM + d] = o;
    }
}

// ---------------------------------------------------------------------------
// Launch
// ---------------------------------------------------------------------------
extern "C" void kernel_launch(void* const* d_in, const int* in_sizes, int n_in,
                              void* d_out, int out_size, void* d_ws, size_t ws_size,
                              hipStream_t stream) {
    const float* x     = (const float*)d_in[0];
    const float* wq    = (const float*)d_in[1];
    const float* bq    = (const float*)d_in[2];
    const float* wk    = (const float*)d_in[3];
    const float* bk    = (const float*)d_in[4];
    const float* wv    = (const float*)d_in[5];
    const float* bv    = (const float*)d_in[6];
    const float* wo    = (const float*)d_in[7];
    const float* bo    = (const float*)d_in[8];
    const float* ln1g  = (const float*)d_in[9];
    const float* ln1b  = (const float*)d_in[10];
    const float* w1    = (const float*)d_in[11];
    const float* b1    = (const float*)d_in[12];
    const float* w2    = (const float*)d_in[13];
    const float* b2    = (const float*)d_in[14];
    const float* ln2g  = (const float*)d_in[15];
    const float* ln2b  = (const float*)d_in[16];
    float* out = (float*)d_out;

    // workspace layout (bytes) — total 65,020,928
    char* ws = (char*)d_ws;
    short* qkvb  = (short*)(ws + 0);             // [TB,2304] bf16  0 .. 18,874,368
    short* ctxb  = (short*)(ws + 18874368);      // [TB,768]  bf16  .. 25,165,824
    short* hb    = (short*)(ws + 0);             // [TB,3072] bf16  (reuses qkvb+ctxb)
    short* xb    = (short*)(ws + 25165824);      // [TB,768]  bf16  .. 31,457,280
    short* Opart = (short*)(ws + 25165824);      // 4x[TB,768] bf16 .. 50,331,648 (over xb)
    float* lpart = (float*)(ws + 50331648);      // 4x[TB,8]  f32   .. 50,855,936
    short* tmpb  = (short*)(ws + 25165824);      // [TB,768]  bf16  (over dead Opart)
    short* x1b   = (short*)(ws + 31457280);      // [TB,768]  bf16  (over dead Opart)
    short* wqkv  = (short*)(ws + 50855936);      // [2304,768] bf16 .. 54,394,880
    short* wob   = (short*)(ws + 54394880);      // [768,768]  bf16 .. 55,574,528
    short* w1b   = (short*)(ws + 55574528);      // [3072,768] bf16 .. 60,293,120
    short* w2b   = (short*)(ws + 60293120);      // [768,3072] bf16 .. 65,011,712
    float* bqkv  = (float*)(ws + 65011712);      // [2304] f32      .. 65,020,928

    // fused fp32->bf16 conversions (wq pre-scaled by scale*log2e)
    CvtArgs ca;
    ca.src[0] = x;  ca.dst[0] = xb;   ca.scl[0] = 1.f;
    ca.src[1] = wq; ca.dst[1] = wqkv; ca.scl[1] = SC_LOG2E;
    ca.src[2] = wk; ca.dst[2] = wqkv + 768 * 768;     ca.scl[2] = 1.f;
    ca.src[3] = wv; ca.dst[3] = wqkv + 2 * 768 * 768; ca.scl[3] = 1.f;
    ca.src[4] = wo; ca.dst[4] = wob;  ca.scl[4] = 1.f;
    ca.src[5] = w1; ca.dst[5] = w1b;  ca.scl[5] = 1.f;
    ca.src[6] = w2; ca.dst[6] = w2b;  ca.scl[6] = 1.f;
    const int n4[7] = {TB * D_DIM / 4, 768 * 768 / 4, 768 * 768 / 4, 768 * 768 / 4,
                       768 * 768 / 4, FFN * 768 / 4, 768 * FFN / 4};
    int acc4 = 0;
    for (int i = 0; i < 7; ++i) { acc4 += n4[i]; ca.end4[i] = acc4; }
    cvt_all<<<(acc4 + 255) / 256, 256, 0, stream>>>(ca, acc4);
    concat_bias<<<(QKV_LD + 255) / 256, 256, 0, stream>>>(bq, bk, bv, bqkv);

    // fused QKV projection: [TB,2304] = xb @ wqkv^T + bqkv
    gemm_mfma<128, short, false><<<dim3(QKV_LD / 128, TB / 128), 256, 0, stream>>>(
        xb, wqkv, bqkv, qkvb, TB, QKV_LD, D_DIM);

    // attention (v5: 4-wave blocks, split-K x4, bare-v_exp softmax) + combine
    attn_mfma<<<dim3(T_LEN / 128, B_SZ * H_NUM, NSPLIT), dim3(256), 0, stream>>>(
        qkvb, Opart, lpart);
    attn_combine<<<dim3(TB), 256, 0, stream>>>(Opart, lpart, ctxb);

    // out projection (bf16 out) + LN1 (bf16 out)
    gemm_mfma<64, short, false><<<dim3(D_DIM / 64, TB / 128), 256, 0, stream>>>(
        ctxb, wob, bo, tmpb, TB, D_DIM, D_DIM);
    ln_residual<float, short><<<dim3(TB), 256, 0, stream>>>(x, tmpb, ln1g, ln1b, x1b);

    // FFN
    gemm_mfma<128, short, true><<<dim3(FFN / 128, TB / 128), 256, 0, stream>>>(
        x1b, w1b, b1, hb, TB, FFN, D_DIM);
    gemm_mfma<64, short, false><<<dim3(D_DIM / 64, TB / 128), 256, 0, stream>>>(
        hb, w2b, b2, tmpb, TB, D_DIM, FFN);
    ln_residual<short, float><<<dim3(TB), 256, 0, stream>>>(x1b, tmpb, ln2g, ln2b, out);
}

// Round 4
// 309.664 us; speedup vs baseline: 1.1395x; 1.0363x over previous
//
#include <hip/hip_runtime.h>
#include <hip/hip_bf16.h>
#include <math.h>

// Problem constants (fixed by the reference)
constexpr int T_LEN = 2048;
constexpr int B_SZ  = 2;
constexpr int D_DIM = 768;
constexpr int H_NUM = 8;
constexpr int HD    = 96;        // D/H
constexpr int FFN   = 3072;
constexpr float EPS = 1e-5f;
constexpr int TB    = T_LEN * B_SZ;   // 4096 rows
constexpr int QKV_LD = 3 * D_DIM;     // 2304
constexpr int NSPLIT = 4;             // attention split-K factor
constexpr int CHUNK  = T_LEN / NSPLIT;   // 512 keys per block
// (1/sqrt(96)) * log2(e): folded into wq/bq so softmax is a bare v_exp (2^x)
constexpr float SC_LOG2E = 0.14724444458547f;

typedef __attribute__((ext_vector_type(8)))  short short8;
typedef __attribute__((ext_vector_type(4)))  short short4v;
typedef __attribute__((ext_vector_type(2)))  short short2v;
typedef __attribute__((ext_vector_type(4)))  float f32x4;
typedef __attribute__((ext_vector_type(16))) float f32x16;

__device__ __forceinline__ short f2bf(float f) {
    union { float f; unsigned u; } v; v.f = f;
    return (short)((v.u + 0x7FFFu + ((v.u >> 16) & 1u)) >> 16);   // RNE
}
__device__ __forceinline__ float bf2f(short s) {
    union { unsigned u; float f; } v;
    v.u = ((unsigned)(unsigned short)s) << 16;
    return v.f;
}
// packed f32x2 -> bf16x2 (V_CVT_PK_BF16_F32 on gfx950); a in low half
__device__ __forceinline__ unsigned pkbf(float a, float b) {
    union { __hip_bfloat162 h; unsigned u; } v;
    v.h = __float22bfloat162_rn(make_float2(a, b));
    return v.u;
}

// async global->LDS, 16B per lane; LDS dst = wave-uniform base + lane*16
__device__ __forceinline__ void async_ld16(const short* g, short* l) {
    __builtin_amdgcn_global_load_lds(
        (const __attribute__((address_space(1))) unsigned int*)g,
        (__attribute__((address_space(3))) unsigned int*)l, 16, 0, 0);
}

// ---------------------------------------------------------------------------
// Prep: fused fp32 -> bf16 conversion over 7 segments (x + 6 weight blobs),
// with a per-segment scale (wq is pre-scaled by SC_LOG2E so attention's
// softmax exp becomes a bare v_exp_f32).
// ---------------------------------------------------------------------------
struct CvtArgs {
    const float* src[7];
    short*       dst[7];
    float        scl[7];
    int          end4[7];   // cumulative segment ends, in float4 units
};

__global__ __launch_bounds__(256)
void cvt_all(CvtArgs a, int total4) {
    const int i = blockIdx.x * 256 + threadIdx.x;
    if (i >= total4) return;
    int s = 0;
    while (i >= a.end4[s]) ++s;
    const int base = s ? a.end4[s - 1] : 0;
    const int j = i - base;
    const float sc = a.scl[s];
    const float4 v = ((const float4*)a.src[s])[j];
    short4v o;
    o[0] = f2bf(v.x * sc); o[1] = f2bf(v.y * sc);
    o[2] = f2bf(v.z * sc); o[3] = f2bf(v.w * sc);
    *(short4v*)(a.dst[s] + (size_t)j * 4) = o;
}

__global__ __launch_bounds__(256)
void concat_bias(const float* __restrict__ bq, const float* __restrict__ bk,
                 const float* __restrict__ bv, float* __restrict__ dst) {
    const int i = blockIdx.x * 256 + threadIdx.x;
    if (i >= QKV_LD) return;
    dst[i] = (i < 768) ? bq[i] * SC_LOG2E : (i < 1536 ? bk[i - 768] : bv[i - 1536]);
}

// ---------------------------------------------------------------------------
// bf16 MFMA GEMM: C[M,N] = A[M,K] @ W[N,K]^T + bias[N]  (optional ReLU)
// BM(M) x BN tile, BK=32, 256 threads = 4 waves, single-buffer (R2's dbuf
// regressed). R4: BM templated. BM=64 doubles the grid for the narrow-N
// GEMMs (Wo, FFN2 were 384 blocks = 1.5/CU -> latency chain fully exposed:
// 62.5us/96 steps = 1560 cyc/step at 14% occupancy, MfmaUtil 11%).
// ---------------------------------------------------------------------------
template <int BM, int BN, typename OutT, bool RELU>
__global__ __launch_bounds__(256)
void gemm_mfma(const short* __restrict__ A, const short* __restrict__ W,
               const float* __restrict__ bias, OutT* __restrict__ C,
               int M, int N, int K) {
    constexpr int MI = BM / 32;   // 16-row tiles per wave
    constexpr int NI = BN / 32;   // 16-col tiles per wave
    __shared__ __align__(16) short As[BM * 32];
    __shared__ __align__(16) short Bs[BN * 32];

    const int tid  = threadIdx.x;
    const int w    = tid >> 6;
    const int lane = tid & 63;
    const int l16  = lane & 15;
    const int q4   = lane >> 4;          // 0..3
    const int row0 = blockIdx.y * BM;
    const int col0 = blockIdx.x * BN;
    const int wm   = (w >> 1) * (BM / 2); // wave m-offset in tile
    const int wn   = (w & 1) * (BN / 2);  // wave n-offset in tile

    const short* gA0 = A + (size_t)(row0 + (tid >> 2)) * K + (tid & 3) * 8;
    const short* gA1 = gA0 + (size_t)64 * K;          // BM==128 only
    const short* gB0 = W + (size_t)(col0 + (tid >> 2)) * K + (tid & 3) * 8;
    const short* gB1 = gB0 + (size_t)64 * K;          // BN==128 only
    short* ldsA0 = As + w * 512;           // wave-uniform bases
    short* ldsA1 = As + 2048 + w * 512;
    short* ldsB0 = Bs + w * 512;
    short* ldsB1 = Bs + 2048 + w * 512;

    f32x4 acc[MI][NI];
#pragma unroll
    for (int mi = 0; mi < MI; ++mi)
#pragma unroll
        for (int ni = 0; ni < NI; ++ni)
#pragma unroll
            for (int r = 0; r < 4; ++r) acc[mi][ni][r] = 0.f;

    for (int k0 = 0; k0 < K; k0 += 32) {
        async_ld16(gA0, ldsA0);
        if constexpr (BM == 128) async_ld16(gA1, ldsA1);
        async_ld16(gB0, ldsB0);
        if constexpr (BN == 128) async_ld16(gB1, ldsB1);
        gA0 += 32; gB0 += 32;
        if constexpr (BM == 128) gA1 += 32;
        if constexpr (BN == 128) gB1 += 32;
        __syncthreads();   // drain glds

        short8 af[MI], bfr[NI];
#pragma unroll
        for (int mi = 0; mi < MI; ++mi)
            af[mi] = *(const short8*)&As[(wm + mi * 16 + l16) * 32 + q4 * 8];
#pragma unroll
        for (int ni = 0; ni < NI; ++ni)
            bfr[ni] = *(const short8*)&Bs[(wn + ni * 16 + l16) * 32 + q4 * 8];
#pragma unroll
        for (int mi = 0; mi < MI; ++mi)
#pragma unroll
            for (int ni = 0; ni < NI; ++ni)
                acc[mi][ni] = __builtin_amdgcn_mfma_f32_16x16x32_bf16(
                    af[mi], bfr[ni], acc[mi][ni], 0, 0, 0);
        __syncthreads();
    }

    float bcol[NI];
#pragma unroll
    for (int ni = 0; ni < NI; ++ni) bcol[ni] = bias[col0 + wn + ni * 16 + l16];
#pragma unroll
    for (int mi = 0; mi < MI; ++mi) {
#pragma unroll
        for (int r = 0; r < 4; ++r) {
            const int row = row0 + wm + mi * 16 + q4 * 4 + r;
#pragma unroll
            for (int ni = 0; ni < NI; ++ni) {
                float v = acc[mi][ni][r] + bcol[ni];
                if (RELU) v = fmaxf(v, 0.f);
                const int col = col0 + wn + ni * 16 + l16;
                if constexpr (sizeof(OutT) == 2)
                    C[(size_t)row * N + col] = (OutT)f2bf(v);
                else
                    C[(size_t)row * N + col] = v;
            }
        }
    }
}

// ---------------------------------------------------------------------------
// MFMA bf16 flash attention v5: split-K + no-max softmax, 4-WAVE blocks.
// 128 q-rows per block (4 waves x 32 rows), grid (T/128, B*H, NSPLIT)
// = 1024 blocks. K/V staging is per-KEY work paid once per block:
//   waves 0-1 stage K (3 b128 loads+writes/lane),
//   waves 2-3 stage V (2-key transpose: 24 extracts + 12 b32 writes/lane).
// QK/softmax/PV per wave on its own 32 q-rows. Conflict-free Ks[2][32][56].
// (R3 validated: attn dropped out of top-5, was 72.7us.)
// ---------------------------------------------------------------------------
__global__ __launch_bounds__(256)
void attn_mfma(const short* __restrict__ qkv, short* __restrict__ Opart,
               float* __restrict__ lpart) {
    __shared__ short Ks[2][32][56];  // [d-half][key][d%48] bf16, conflict-free
    __shared__ short Vt[128][44];    // [d][key] bf16, stride 44
    __shared__ short Pw[4][32][36];  // per-wave P, stride 36

    const int tid  = threadIdx.x;
    const int w    = tid >> 6;
    const int lane = tid & 63;
    const int l31  = lane & 31;
    const int h5   = lane >> 5;
    const int t0   = blockIdx.x * 128;
    const int bh   = blockIdx.y;
    const int split = blockIdx.z;
    const int b    = bh >> 3;
    const int h    = bh & 7;

    // Vt rows 96..127: row 96 = ones (denominator column), rest zero
    for (int i = tid; i < 32 * 44; i += 256) {
        const int rr = i / 44, cc = i % 44;
        Vt[96 + rr][cc] = (rr == 0 && cc < 32) ? (short)0x3F80 : (short)0;
    }

    // Q fragments straight from global bf16 (wave-private 32 q-rows)
    short8 qf[6];
    {
        const int qrow = t0 + w * 32 + l31;
        const short* qb = qkv + ((size_t)qrow * B_SZ + b) * QKV_LD + h * HD;
#pragma unroll
        for (int ks = 0; ks < 6; ++ks)
            qf[ks] = *(const short8*)&qb[ks * 16 + h5 * 8];
    }

    // --- staging assignments (wave-specialized), chunk-local keys ---
    // waves 0,1 (tid 0..127): K. Each (key, quarter) once: 32 keys x 4
    // quarters of 24 d (48 B = 3 short8).
    const int k_row = tid >> 2;                   // 0..31 (valid for tid<128)
    const int k_q   = tid & 3;                    // d-quarter
    const short* gK = qkv + ((size_t)(split * CHUNK + k_row) * B_SZ + b) * QKV_LD
                      + D_DIM + h * HD + k_q * 24;
    // waves 2,3 (ll = tid-128, 0..127): V. 8 d-groups x 16 key-pairs.
    const int ll = tid - 128;
    const int dg = (ll & 7) * 12;                 // d-group
    const int kg = (ll >> 3) * 2;                 // key pair
    const short* gV = qkv + ((size_t)(split * CHUNK + kg) * B_SZ + b) * QKV_LD
                      + 2 * D_DIM + h * HD + dg;
    const size_t step  = (size_t)32 * B_SZ * QKV_LD;
    const size_t vrow  = (size_t)B_SZ * QKV_LD;   // one key row

    f32x16 oacc[4];
#pragma unroll
    for (int nt = 0; nt < 4; ++nt)
#pragma unroll
        for (int r = 0; r < 16; ++r) oacc[nt][r] = 0.f;

    // prefetch tile 0 (wave-specialized, registers)
    short8  kpf[3];
    short4v vpf[2][3];
    if (w < 2) {
#pragma unroll
        for (int j = 0; j < 3; ++j) kpf[j] = *(const short8*)(gK + j * 8);
    } else {
#pragma unroll
        for (int r = 0; r < 2; ++r)
#pragma unroll
            for (int c = 0; c < 3; ++c)
                vpf[r][c] = *(const short4v*)(gV + r * vrow + c * 4);
    }

    for (int it = 0; it < CHUNK / 32; ++it) {
        __syncthreads();   // previous tile fully consumed by all waves
        if (w < 2) {
#pragma unroll
            for (int j = 0; j < 3; ++j)
                *(short8*)&Ks[k_q >> 1][k_row][(k_q & 1) * 24 + j * 8] = kpf[j];
        } else {
#pragma unroll
            for (int d = 0; d < 12; ++d) {
                short2v t;
                t[0] = vpf[0][d >> 2][d & 3];
                t[1] = vpf[1][d >> 2][d & 3];
                *(short2v*)&Vt[dg + d][kg] = t;
            }
        }
        __syncthreads();

        // prefetch next tile (latency hides behind this tile's compute)
        if (it + 1 < CHUNK / 32) {
            const size_t off = (size_t)(it + 1) * step;
            if (w < 2) {
#pragma unroll
                for (int j = 0; j < 3; ++j)
                    kpf[j] = *(const short8*)(gK + off + j * 8);
            } else {
#pragma unroll
                for (int r = 0; r < 2; ++r)
#pragma unroll
                    for (int c = 0; c < 3; ++c)
                        vpf[r][c] = *(const short4v*)(gV + off + r * vrow + c * 4);
            }
        }

        // S = Q.K^T  (Q pre-scaled by scale*log2e)
        f32x16 sa;
#pragma unroll
        for (int r = 0; r < 16; ++r) sa[r] = 0.f;
#pragma unroll
        for (int ks = 0; ks < 6; ++ks) {
            const int half = ks / 3;                   // compile-time per ks
            const int base = ks * 16 - half * 48;      // local d within half
            const short8 kf = *(const short8*)&Ks[half][l31][base + h5 * 8];
            sa = __builtin_amdgcn_mfma_f32_32x32x16_bf16(qf[ks], kf, sa, 0, 0, 0);
        }

        // P = 2^S (bare v_exp); packed cvt to bf16; C-layout -> LDS -> A-layout
        float pvx[16];
#pragma unroll
        for (int r = 0; r < 16; ++r) pvx[r] = __builtin_amdgcn_exp2f(sa[r]);
#pragma unroll
        for (int rp = 0; rp < 8; ++rp) {
            const unsigned u = pkbf(pvx[2 * rp], pvx[2 * rp + 1]);
            const int row = ((2 * rp) & 3) + 8 * ((2 * rp) >> 2) + 4 * h5;
            Pw[w][row][l31]     = (short)(u & 0xFFFFu);
            Pw[w][row + 1][l31] = (short)(u >> 16);
        }

        // O += P.V  (+ denominator column in n-tile 3)
#pragma unroll
        for (int ks2 = 0; ks2 < 2; ++ks2) {
            const short* pp = &Pw[w][l31][ks2 * 16 + h5 * 8];
            const short4v plo = *(const short4v*)pp;
            const short4v phi = *(const short4v*)(pp + 4);
            const short8 pfr = __builtin_shufflevector(plo, phi, 0, 1, 2, 3, 4, 5, 6, 7);
#pragma unroll
            for (int nt = 0; nt < 4; ++nt) {
                const short* vp = &Vt[nt * 32 + l31][ks2 * 16 + h5 * 8];
                const short4v vlo = *(const short4v*)vp;
                const short4v vhi = *(const short4v*)(vp + 4);
                const short8 vf = __builtin_shufflevector(vlo, vhi, 0, 1, 2, 3, 4, 5, 6, 7);
                oacc[nt] = __builtin_amdgcn_mfma_f32_32x32x16_bf16(pfr, vf, oacc[nt], 0, 0, 0);
            }
        }
    }

    // epilogue: store UNNORMALIZED O-partial (bf16) + l-partial (f32)
#pragma unroll
    for (int r = 0; r < 16; ++r) {
        const int row  = (r & 3) + 8 * (r >> 2) + 4 * h5;
        const int t    = t0 + w * 32 + row;
        const int grow = t * B_SZ + b;
        short* op = Opart + ((size_t)split * TB + grow) * D_DIM + h * HD;
#pragma unroll
        for (int nt = 0; nt < 3; ++nt)
            op[nt * 32 + l31] = f2bf(oacc[nt][r]);
        if (l31 == 0)
            lpart[((size_t)split * TB + grow) * H_NUM + h] = oacc[3][r];
    }
}

// ---------------------------------------------------------------------------
// Combine: ctx = (sum_c Opart[c]) / (sum_c lpart[c]).  One block per row,
// 192 active lanes x 4 d each, short4 vector loads.
// ---------------------------------------------------------------------------
__global__ __launch_bounds__(256)
void attn_combine(const short* __restrict__ Opart, const float* __restrict__ lpart,
                  short* __restrict__ ctx) {
    const int row = blockIdx.x;
    const int tid = threadIdx.x;
    if (tid >= 192) return;
    const int d = tid * 4;
    const int h = d / 96;
    float o0 = 0.f, o1 = 0.f, o2 = 0.f, o3 = 0.f, l = 0.f;
#pragma unroll
    for (int c = 0; c < NSPLIT; ++c) {
        const short4v v = *(const short4v*)&Opart[((size_t)c * TB + row) * D_DIM + d];
        o0 += bf2f(v[0]); o1 += bf2f(v[1]); o2 += bf2f(v[2]); o3 += bf2f(v[3]);
        l += lpart[((size_t)c * TB + row) * H_NUM + h];
    }
    const float iv = 1.f / l;
    short4v r;
    r[0] = f2bf(o0 * iv); r[1] = f2bf(o1 * iv);
    r[2] = f2bf(o2 * iv); r[3] = f2bf(o3 * iv);
    *(short4v*)&ctx[(size_t)row * D_DIM + d] = r;
}

// ---------------------------------------------------------------------------
// Fused residual + LayerNorm: out = LN(xres + y)*g + b.  (unchanged)
// ---------------------------------------------------------------------------
template <typename XT, typename OT>
__global__ __launch_bounds__(256)
void ln_residual(const XT* __restrict__ xres, const short* __restrict__ y,
                 const float* __restrict__ g, const float* __restrict__ bb,
                 OT* __restrict__ out) {
    const int row = blockIdx.x;
    const int tid = threadIdx.x;
    const XT*    xr = xres + (size_t)row * D_DIM;
    const short* yr = y + (size_t)row * D_DIM;

    float vals[3];
    float s = 0.f, s2 = 0.f;
#pragma unroll
    for (int i = 0; i < 3; ++i) {
        const int d = tid + i * 256;
        float xv;
        if constexpr (sizeof(XT) == 2) xv = bf2f((short)xr[d]);
        else                           xv = (float)xr[d];
        const float t = xv + bf2f(yr[d]);
        vals[i] = t;
        s += t;
        s2 = fmaf(t, t, s2);
    }
#pragma unroll
    for (int off = 32; off > 0; off >>= 1) {
        s  += __shfl_down(s, off);
        s2 += __shfl_down(s2, off);
    }
    __shared__ float red_s[4], red_s2[4];
    const int wid = tid >> 6, lane = tid & 63;
    if (lane == 0) { red_s[wid] = s; red_s2[wid] = s2; }
    __syncthreads();
    __shared__ float sh_mean, sh_rstd;
    if (tid == 0) {
        const float ts  = red_s[0] + red_s[1] + red_s[2] + red_s[3];
        const float ts2 = red_s2[0] + red_s2[1] + red_s2[2] + red_s2[3];
        const float mean = ts * (1.f / D_DIM);
        const float var  = ts2 * (1.f / D_DIM) - mean * mean;
        sh_mean = mean;
        sh_rstd = rsqrtf(var + EPS);
    }
    __syncthreads();
    const float mean = sh_mean, rstd = sh_rstd;
#pragma unroll
    for (int i = 0; i < 3; ++i) {
        const int d = tid + i * 256;
        const float o = (vals[i] - mean) * rstd * g[d] + bb[d];
        if constexpr (sizeof(OT) == 2)
            out[(size_t)row * D_DIM + d] = (OT)f2bf(o);
        else
            out[(size_t)row * D_DIM + d] = o;
    }
}

// ---------------------------------------------------------------------------
// Launch
// ---------------------------------------------------------------------------
extern "C" void kernel_launch(void* const* d_in, const int* in_sizes, int n_in,
                              void* d_out, int out_size, void* d_ws, size_t ws_size,
                              hipStream_t stream) {
    const float* x     = (const float*)d_in[0];
    const float* wq    = (const float*)d_in[1];
    const float* bq    = (const float*)d_in[2];
    const float* wk    = (const float*)d_in[3];
    const float* bk    = (const float*)d_in[4];
    const float* wv    = (const float*)d_in[5];
    const float* bv    = (const float*)d_in[6];
    const float* wo    = (const float*)d_in[7];
    const float* bo    = (const float*)d_in[8];
    const float* ln1g  = (const float*)d_in[9];
    const float* ln1b  = (const float*)d_in[10];
    const float* w1    = (const float*)d_in[11];
    const float* b1    = (const float*)d_in[12];
    const float* w2    = (const float*)d_in[13];
    const float* b2    = (const float*)d_in[14];
    const float* ln2g  = (const float*)d_in[15];
    const float* ln2b  = (const float*)d_in[16];
    float* out = (float*)d_out;

    // workspace layout (bytes) — total 65,020,928
    char* ws = (char*)d_ws;
    short* qkvb  = (short*)(ws + 0);             // [TB,2304] bf16  0 .. 18,874,368
    short* ctxb  = (short*)(ws + 18874368);      // [TB,768]  bf16  .. 25,165,824
    short* hb    = (short*)(ws + 0);             // [TB,3072] bf16  (reuses qkvb+ctxb)
    short* xb    = (short*)(ws + 25165824);      // [TB,768]  bf16  .. 31,457,280
    short* Opart = (short*)(ws + 25165824);      // 4x[TB,768] bf16 .. 50,331,648 (over xb)
    float* lpart = (float*)(ws + 50331648);      // 4x[TB,8]  f32   .. 50,855,936
    short* tmpb  = (short*)(ws + 25165824);      // [TB,768]  bf16  (over dead Opart)
    short* x1b   = (short*)(ws + 31457280);      // [TB,768]  bf16  (over dead Opart)
    short* wqkv  = (short*)(ws + 50855936);      // [2304,768] bf16 .. 54,394,880
    short* wob   = (short*)(ws + 54394880);      // [768,768]  bf16 .. 55,574,528
    short* w1b   = (short*)(ws + 55574528);      // [3072,768] bf16 .. 60,293,120
    short* w2b   = (short*)(ws + 60293120);      // [768,3072] bf16 .. 65,011,712
    float* bqkv  = (float*)(ws + 65011712);      // [2304] f32      .. 65,020,928

    // fused fp32->bf16 conversions (wq pre-scaled by scale*log2e)
    CvtArgs ca;
    ca.src[0] = x;  ca.dst[0] = xb;   ca.scl[0] = 1.f;
    ca.src[1] = wq; ca.dst[1] = wqkv; ca.scl[1] = SC_LOG2E;
    ca.src[2] = wk; ca.dst[2] = wqkv + 768 * 768;     ca.scl[2] = 1.f;
    ca.src[3] = wv; ca.dst[3] = wqkv + 2 * 768 * 768; ca.scl[3] = 1.f;
    ca.src[4] = wo; ca.dst[4] = wob;  ca.scl[4] = 1.f;
    ca.src[5] = w1; ca.dst[5] = w1b;  ca.scl[5] = 1.f;
    ca.src[6] = w2; ca.dst[6] = w2b;  ca.scl[6] = 1.f;
    const int n4[7] = {TB * D_DIM / 4, 768 * 768 / 4, 768 * 768 / 4, 768 * 768 / 4,
                       768 * 768 / 4, FFN * 768 / 4, 768 * FFN / 4};
    int acc4 = 0;
    for (int i = 0; i < 7; ++i) { acc4 += n4[i]; ca.end4[i] = acc4; }
    cvt_all<<<(acc4 + 255) / 256, 256, 0, stream>>>(ca, acc4);
    concat_bias<<<(QKV_LD + 255) / 256, 256, 0, stream>>>(bq, bk, bv, bqkv);

    // fused QKV projection: [TB,2304] = xb @ wqkv^T + bqkv  (control: BM=128)
    gemm_mfma<128, 128, short, false><<<dim3(QKV_LD / 128, TB / 128), 256, 0, stream>>>(
        xb, wqkv, bqkv, qkvb, TB, QKV_LD, D_DIM);

    // attention (v5: 4-wave blocks, split-K x4, bare-v_exp softmax) + combine
    attn_mfma<<<dim3(T_LEN / 128, B_SZ * H_NUM, NSPLIT), dim3(256), 0, stream>>>(
        qkvb, Opart, lpart);
    attn_combine<<<dim3(TB), 256, 0, stream>>>(Opart, lpart, ctxb);

    // out projection: BM=64 -> 768 blocks (was 384 = 1.5/CU, latency-exposed)
    gemm_mfma<64, 64, short, false><<<dim3(D_DIM / 64, TB / 64), 256, 0, stream>>>(
        ctxb, wob, bo, tmpb, TB, D_DIM, D_DIM);
    ln_residual<float, short><<<dim3(TB), 256, 0, stream>>>(x, tmpb, ln1g, ln1b, x1b);

    // FFN1 (control: BM=128)
    gemm_mfma<128, 128, short, true><<<dim3(FFN / 128, TB / 128), 256, 0, stream>>>(
        x1b, w1b, b1, hb, TB, FFN, D_DIM);
    // FFN2: BM=64 -> 768 blocks (was 384; worst dispatch @62.5us, MfmaUtil 11%)
    gemm_mfma<64, 64, short, false><<<dim3(D_DIM / 64, TB / 64), 256, 0, stream>>>(
        hb, w2b, b2, tmpb, TB, D_DIM, FFN);
    ln_residual<short, float><<<dim3(TB), 256, 0, stream>>>(x1b, tmpb, ln2g, ln2b, out);
}

// Round 5
// 300.008 us; speedup vs baseline: 1.1762x; 1.0322x over previous
//
#include <hip/hip_runtime.h>
#include <hip/hip_bf16.h>
#include <math.h>

// Problem constants (fixed by the reference)
constexpr int T_LEN = 2048;
constexpr int B_SZ  = 2;
constexpr int D_DIM = 768;
constexpr int H_NUM = 8;
constexpr int HD    = 96;        // D/H
constexpr int FFN   = 3072;
constexpr float EPS = 1e-5f;
constexpr int TB    = T_LEN * B_SZ;   // 4096 rows
constexpr int QKV_LD = 3 * D_DIM;     // 2304
constexpr int NSPLIT = 4;             // attention split-K factor
constexpr int CHUNK  = T_LEN / NSPLIT;   // 512 keys per block
// (1/sqrt(96)) * log2(e): folded into wq/bq so softmax is a bare v_exp (2^x)
constexpr float SC_LOG2E = 0.14724444458547f;

typedef __attribute__((ext_vector_type(8)))  short short8;
typedef __attribute__((ext_vector_type(4)))  short short4v;
typedef __attribute__((ext_vector_type(2)))  short short2v;
typedef __attribute__((ext_vector_type(4)))  float f32x4;
typedef __attribute__((ext_vector_type(16))) float f32x16;

__device__ __forceinline__ short f2bf(float f) {
    union { float f; unsigned u; } v; v.f = f;
    return (short)((v.u + 0x7FFFu + ((v.u >> 16) & 1u)) >> 16);   // RNE
}
__device__ __forceinline__ float bf2f(short s) {
    union { unsigned u; float f; } v;
    v.u = ((unsigned)(unsigned short)s) << 16;
    return v.f;
}
// packed f32x2 -> bf16x2 (V_CVT_PK_BF16_F32 on gfx950); a in low half
__device__ __forceinline__ unsigned pkbf(float a, float b) {
    union { __hip_bfloat162 h; unsigned u; } v;
    v.h = __float22bfloat162_rn(make_float2(a, b));
    return v.u;
}

// async global->LDS, 16B per lane; LDS dst = wave-uniform base + lane*16
__device__ __forceinline__ void async_ld16(const short* g, short* l) {
    __builtin_amdgcn_global_load_lds(
        (const __attribute__((address_space(1))) unsigned int*)g,
        (__attribute__((address_space(3))) unsigned int*)l, 16, 0, 0);
}

// ---------------------------------------------------------------------------
// Prep: fused fp32 -> bf16 conversion over 7 segments (x + 6 weight blobs),
// with a per-segment scale (wq is pre-scaled by SC_LOG2E so attention's
// softmax exp becomes a bare v_exp_f32).
// ---------------------------------------------------------------------------
struct CvtArgs {
    const float* src[7];
    short*       dst[7];
    float        scl[7];
    int          end4[7];   // cumulative segment ends, in float4 units
};

__global__ __launch_bounds__(256)
void cvt_all(CvtArgs a, int total4) {
    const int i = blockIdx.x * 256 + threadIdx.x;
    if (i >= total4) return;
    int s = 0;
    while (i >= a.end4[s]) ++s;
    const int base = s ? a.end4[s - 1] : 0;
    const int j = i - base;
    const float sc = a.scl[s];
    const float4 v = ((const float4*)a.src[s])[j];
    short4v o;
    o[0] = f2bf(v.x * sc); o[1] = f2bf(v.y * sc);
    o[2] = f2bf(v.z * sc); o[3] = f2bf(v.w * sc);
    *(short4v*)(a.dst[s] + (size_t)j * 4) = o;
}

__global__ __launch_bounds__(256)
void concat_bias(const float* __restrict__ bq, const float* __restrict__ bk,
                 const float* __restrict__ bv, float* __restrict__ dst) {
    const int i = blockIdx.x * 256 + threadIdx.x;
    if (i >= QKV_LD) return;
    dst[i] = (i < 768) ? bq[i] * SC_LOG2E : (i < 1536 ? bk[i - 768] : bv[i - 1536]);
}

// ---------------------------------------------------------------------------
// bf16 MFMA GEMM: C[M,N] = A[M,K] @ W[N,K]^T + bias[N]  (optional ReLU)
// R5: counted-vmcnt 2-phase pipeline (T3+T4 minimum). R4 showed 1417
// cyc/K-step = full load-latency chain exposed every step because
// __syncthreads drains vmcnt(0) right after the load issue (R2's dbuf
// failed for exactly this reason). Now: raw s_barrier + s_waitcnt vmcnt(4)
// -- tile t+1's 4 glds stay IN FLIGHT across tile t's MFMA phase.
// All four shapes have exactly 4 glds/thread/stage -> constant vmcnt(4).
// Hazards: barrier1 (after counted wait) = buf[t] fully written for all
// waves; barrier2 (after compute) = buf[t] fully read before t+2's stage
// overwrites it. Same 2 barriers/step as before -- only the drain moved.
// ---------------------------------------------------------------------------
template <int BM, int BN, int BK, typename OutT, bool RELU>
__global__ __launch_bounds__(256)
void gemm_mfma(const short* __restrict__ A, const short* __restrict__ W,
               const float* __restrict__ bias, OutT* __restrict__ C,
               int M, int N, int K) {
    constexpr int MI = BM / 32;   // 16-row tiles per wave
    constexpr int NI = BN / 32;   // 16-col tiles per wave
    constexpr int KI = BK / 32;   // k-substeps per tile
    static_assert(BM * BK == 4096 && BN * BK == 4096, "4 glds/thread/stage");
    constexpr int ROWSTEP = 2048 / BK;   // rows per 2048-short call chunk
    __shared__ __align__(16) short As[2][4096];
    __shared__ __align__(16) short Bs[2][4096];

    const int tid  = threadIdx.x;
    const int w    = tid >> 6;
    const int lane = tid & 63;
    const int l16  = lane & 15;
    const int q4   = lane >> 4;          // 0..3
    const int row0 = blockIdx.y * BM;
    const int col0 = blockIdx.x * BN;
    const int wm   = (w >> 1) * (BM / 2); // wave m-offset in tile
    const int wn   = (w & 1) * (BN / 2);  // wave n-offset in tile

    // staging: thread covers shorts [c*2048 + tid*8, +8) of each 4096 tile
    const int mA = tid / (BK / 8);
    const int kA = (tid % (BK / 8)) * 8;
    const short* gA0 = A + (size_t)(row0 + mA) * K + kA;
    const short* gA1 = gA0 + (size_t)ROWSTEP * K;
    const short* gB0 = W + (size_t)(col0 + mA) * K + kA;
    const short* gB1 = gB0 + (size_t)ROWSTEP * K;

    f32x4 acc[MI][NI];
#pragma unroll
    for (int mi = 0; mi < MI; ++mi)
#pragma unroll
        for (int ni = 0; ni < NI; ++ni)
#pragma unroll
            for (int r = 0; r < 4; ++r) acc[mi][ni][r] = 0.f;

    auto stage = [&](int buf) {
        async_ld16(gA0, &As[buf][w * 512]);
        async_ld16(gA1, &As[buf][2048 + w * 512]);
        async_ld16(gB0, &Bs[buf][w * 512]);
        async_ld16(gB1, &Bs[buf][2048 + w * 512]);
        gA0 += BK; gA1 += BK; gB0 += BK; gB1 += BK;
    };
    auto compute = [&](int buf) {
#pragma unroll
        for (int ks = 0; ks < KI; ++ks) {
            short8 af[MI], bfr[NI];
#pragma unroll
            for (int mi = 0; mi < MI; ++mi)
                af[mi] = *(const short8*)&As[buf][(wm + mi * 16 + l16) * BK + ks * 32 + q4 * 8];
#pragma unroll
            for (int ni = 0; ni < NI; ++ni)
                bfr[ni] = *(const short8*)&Bs[buf][(wn + ni * 16 + l16) * BK + ks * 32 + q4 * 8];
#pragma unroll
            for (int mi = 0; mi < MI; ++mi)
#pragma unroll
                for (int ni = 0; ni < NI; ++ni)
                    acc[mi][ni] = __builtin_amdgcn_mfma_f32_16x16x32_bf16(
                        af[mi], bfr[ni], acc[mi][ni], 0, 0, 0);
        }
    };

    stage(0);                            // prologue: tile 0 in flight
    const int NT = K / BK;
    for (int t = 0; t < NT; ++t) {
        const int cur = t & 1;
        if (t + 1 < NT) {
            stage(cur ^ 1);              // 4 more glds -> 8 outstanding
            asm volatile("s_waitcnt vmcnt(4)" ::: "memory");  // oldest 4 (tile t) done
        } else {
            asm volatile("s_waitcnt vmcnt(0)" ::: "memory");  // final drain
        }
        __builtin_amdgcn_s_barrier();    // all waves: buf[cur] fully written
        __builtin_amdgcn_sched_barrier(0);
        compute(cur);
        __builtin_amdgcn_s_barrier();    // all waves: buf[cur] fully read
        __builtin_amdgcn_sched_barrier(0);
    }

    float bcol[NI];
#pragma unroll
    for (int ni = 0; ni < NI; ++ni) bcol[ni] = bias[col0 + wn + ni * 16 + l16];
#pragma unroll
    for (int mi = 0; mi < MI; ++mi) {
#pragma unroll
        for (int r = 0; r < 4; ++r) {
            const int row = row0 + wm + mi * 16 + q4 * 4 + r;
#pragma unroll
            for (int ni = 0; ni < NI; ++ni) {
                float v = acc[mi][ni][r] + bcol[ni];
                if (RELU) v = fmaxf(v, 0.f);
                const int col = col0 + wn + ni * 16 + l16;
                if constexpr (sizeof(OutT) == 2)
                    C[(size_t)row * N + col] = (OutT)f2bf(v);
                else
                    C[(size_t)row * N + col] = v;
            }
        }
    }
}

// ---------------------------------------------------------------------------
// MFMA bf16 flash attention v5: split-K + no-max softmax, 4-WAVE blocks.
// 128 q-rows per block (4 waves x 32 rows), grid (T/128, B*H, NSPLIT)
// = 1024 blocks. K/V staging is per-KEY work paid once per block:
//   waves 0-1 stage K (3 b128 loads+writes/lane),
//   waves 2-3 stage V (2-key transpose: 24 extracts + 12 b32 writes/lane).
// QK/softmax/PV per wave on its own 32 q-rows. Conflict-free Ks[2][32][56].
// (R3 validated: attn dropped out of top-5, was 72.7us.)  UNCHANGED (control).
// ---------------------------------------------------------------------------
__global__ __launch_bounds__(256)
void attn_mfma(const short* __restrict__ qkv, short* __restrict__ Opart,
               float* __restrict__ lpart) {
    __shared__ short Ks[2][32][56];  // [d-half][key][d%48] bf16, conflict-free
    __shared__ short Vt[128][44];    // [d][key] bf16, stride 44
    __shared__ short Pw[4][32][36];  // per-wave P, stride 36

    const int tid  = threadIdx.x;
    const int w    = tid >> 6;
    const int lane = tid & 63;
    const int l31  = lane & 31;
    const int h5   = lane >> 5;
    const int t0   = blockIdx.x * 128;
    const int bh   = blockIdx.y;
    const int split = blockIdx.z;
    const int b    = bh >> 3;
    const int h    = bh & 7;

    // Vt rows 96..127: row 96 = ones (denominator column), rest zero
    for (int i = tid; i < 32 * 44; i += 256) {
        const int rr = i / 44, cc = i % 44;
        Vt[96 + rr][cc] = (rr == 0 && cc < 32) ? (short)0x3F80 : (short)0;
    }

    // Q fragments straight from global bf16 (wave-private 32 q-rows)
    short8 qf[6];
    {
        const int qrow = t0 + w * 32 + l31;
        const short* qb = qkv + ((size_t)qrow * B_SZ + b) * QKV_LD + h * HD;
#pragma unroll
        for (int ks = 0; ks < 6; ++ks)
            qf[ks] = *(const short8*)&qb[ks * 16 + h5 * 8];
    }

    // --- staging assignments (wave-specialized), chunk-local keys ---
    // waves 0,1 (tid 0..127): K. Each (key, quarter) once: 32 keys x 4
    // quarters of 24 d (48 B = 3 short8).
    const int k_row = tid >> 2;                   // 0..31 (valid for tid<128)
    const int k_q   = tid & 3;                    // d-quarter
    const short* gK = qkv + ((size_t)(split * CHUNK + k_row) * B_SZ + b) * QKV_LD
                      + D_DIM + h * HD + k_q * 24;
    // waves 2,3 (ll = tid-128, 0..127): V. 8 d-groups x 16 key-pairs.
    const int ll = tid - 128;
    const int dg = (ll & 7) * 12;                 // d-group
    const int kg = (ll >> 3) * 2;                 // key pair
    const short* gV = qkv + ((size_t)(split * CHUNK + kg) * B_SZ + b) * QKV_LD
                      + 2 * D_DIM + h * HD + dg;
    const size_t step  = (size_t)32 * B_SZ * QKV_LD;
    const size_t vrow  = (size_t)B_SZ * QKV_LD;   // one key row

    f32x16 oacc[4];
#pragma unroll
    for (int nt = 0; nt < 4; ++nt)
#pragma unroll
        for (int r = 0; r < 16; ++r) oacc[nt][r] = 0.f;

    // prefetch tile 0 (wave-specialized, registers)
    short8  kpf[3];
    short4v vpf[2][3];
    if (w < 2) {
#pragma unroll
        for (int j = 0; j < 3; ++j) kpf[j] = *(const short8*)(gK + j * 8);
    } else {
#pragma unroll
        for (int r = 0; r < 2; ++r)
#pragma unroll
            for (int c = 0; c < 3; ++c)
                vpf[r][c] = *(const short4v*)(gV + r * vrow + c * 4);
    }

    for (int it = 0; it < CHUNK / 32; ++it) {
        __syncthreads();   // previous tile fully consumed by all waves
        if (w < 2) {
#pragma unroll
            for (int j = 0; j < 3; ++j)
                *(short8*)&Ks[k_q >> 1][k_row][(k_q & 1) * 24 + j * 8] = kpf[j];
        } else {
#pragma unroll
            for (int d = 0; d < 12; ++d) {
                short2v t;
                t[0] = vpf[0][d >> 2][d & 3];
                t[1] = vpf[1][d >> 2][d & 3];
                *(short2v*)&Vt[dg + d][kg] = t;
            }
        }
        __syncthreads();

        // prefetch next tile (latency hides behind this tile's compute)
        if (it + 1 < CHUNK / 32) {
            const size_t off = (size_t)(it + 1) * step;
            if (w < 2) {
#pragma unroll
                for (int j = 0; j < 3; ++j)
                    kpf[j] = *(const short8*)(gK + off + j * 8);
            } else {
#pragma unroll
                for (int r = 0; r < 2; ++r)
#pragma unroll
                    for (int c = 0; c < 3; ++c)
                        vpf[r][c] = *(const short4v*)(gV + off + r * vrow + c * 4);
            }
        }

        // S = Q.K^T  (Q pre-scaled by scale*log2e)
        f32x16 sa;
#pragma unroll
        for (int r = 0; r < 16; ++r) sa[r] = 0.f;
#pragma unroll
        for (int ks = 0; ks < 6; ++ks) {
            const int half = ks / 3;                   // compile-time per ks
            const int base = ks * 16 - half * 48;      // local d within half
            const short8 kf = *(const short8*)&Ks[half][l31][base + h5 * 8];
            sa = __builtin_amdgcn_mfma_f32_32x32x16_bf16(qf[ks], kf, sa, 0, 0, 0);
        }

        // P = 2^S (bare v_exp); packed cvt to bf16; C-layout -> LDS -> A-layout
        float pvx[16];
#pragma unroll
        for (int r = 0; r < 16; ++r) pvx[r] = __builtin_amdgcn_exp2f(sa[r]);
#pragma unroll
        for (int rp = 0; rp < 8; ++rp) {
            const unsigned u = pkbf(pvx[2 * rp], pvx[2 * rp + 1]);
            const int row = ((2 * rp) & 3) + 8 * ((2 * rp) >> 2) + 4 * h5;
            Pw[w][row][l31]     = (short)(u & 0xFFFFu);
            Pw[w][row + 1][l31] = (short)(u >> 16);
        }

        // O += P.V  (+ denominator column in n-tile 3)
#pragma unroll
        for (int ks2 = 0; ks2 < 2; ++ks2) {
            const short* pp = &Pw[w][l31][ks2 * 16 + h5 * 8];
            const short4v plo = *(const short4v*)pp;
            const short4v phi = *(const short4v*)(pp + 4);
            const short8 pfr = __builtin_shufflevector(plo, phi, 0, 1, 2, 3, 4, 5, 6, 7);
#pragma unroll
            for (int nt = 0; nt < 4; ++nt) {
                const short* vp = &Vt[nt * 32 + l31][ks2 * 16 + h5 * 8];
                const short4v vlo = *(const short4v*)vp;
                const short4v vhi = *(const short4v*)(vp + 4);
                const short8 vf = __builtin_shufflevector(vlo, vhi, 0, 1, 2, 3, 4, 5, 6, 7);
                oacc[nt] = __builtin_amdgcn_mfma_f32_32x32x16_bf16(pfr, vf, oacc[nt], 0, 0, 0);
            }
        }
    }

    // epilogue: store UNNORMALIZED O-partial (bf16) + l-partial (f32)
#pragma unroll
    for (int r = 0; r < 16; ++r) {
        const int row  = (r & 3) + 8 * (r >> 2) + 4 * h5;
        const int t    = t0 + w * 32 + row;
        const int grow = t * B_SZ + b;
        short* op = Opart + ((size_t)split * TB + grow) * D_DIM + h * HD;
#pragma unroll
        for (int nt = 0; nt < 3; ++nt)
            op[nt * 32 + l31] = f2bf(oacc[nt][r]);
        if (l31 == 0)
            lpart[((size_t)split * TB + grow) * H_NUM + h] = oacc[3][r];
    }
}

// ---------------------------------------------------------------------------
// Combine: ctx = (sum_c Opart[c]) / (sum_c lpart[c]).  One block per row,
// 192 active lanes x 4 d each, short4 vector loads.
// ---------------------------------------------------------------------------
__global__ __launch_bounds__(256)
void attn_combine(const short* __restrict__ Opart, const float* __restrict__ lpart,
                  short* __restrict__ ctx) {
    const int row = blockIdx.x;
    const int tid = threadIdx.x;
    if (tid >= 192) return;
    const int d = tid * 4;
    const int h = d / 96;
    float o0 = 0.f, o1 = 0.f, o2 = 0.f, o3 = 0.f, l = 0.f;
#pragma unroll
    for (int c = 0; c < NSPLIT; ++c) {
        const short4v v = *(const short4v*)&Opart[((size_t)c * TB + row) * D_DIM + d];
        o0 += bf2f(v[0]); o1 += bf2f(v[1]); o2 += bf2f(v[2]); o3 += bf2f(v[3]);
        l += lpart[((size_t)c * TB + row) * H_NUM + h];
    }
    const float iv = 1.f / l;
    short4v r;
    r[0] = f2bf(o0 * iv); r[1] = f2bf(o1 * iv);
    r[2] = f2bf(o2 * iv); r[3] = f2bf(o3 * iv);
    *(short4v*)&ctx[(size_t)row * D_DIM + d] = r;
}

// ---------------------------------------------------------------------------
// Fused residual + LayerNorm: out = LN(xres + y)*g + b.  (unchanged)
// ---------------------------------------------------------------------------
template <typename XT, typename OT>
__global__ __launch_bounds__(256)
void ln_residual(const XT* __restrict__ xres, const short* __restrict__ y,
                 const float* __restrict__ g, const float* __restrict__ bb,
                 OT* __restrict__ out) {
    const int row = blockIdx.x;
    const int tid = threadIdx.x;
    const XT*    xr = xres + (size_t)row * D_DIM;
    const short* yr = y + (size_t)row * D_DIM;

    float vals[3];
    float s = 0.f, s2 = 0.f;
#pragma unroll
    for (int i = 0; i < 3; ++i) {
        const int d = tid + i * 256;
        float xv;
        if constexpr (sizeof(XT) == 2) xv = bf2f((short)xr[d]);
        else                           xv = (float)xr[d];
        const float t = xv + bf2f(yr[d]);
        vals[i] = t;
        s += t;
        s2 = fmaf(t, t, s2);
    }
#pragma unroll
    for (int off = 32; off > 0; off >>= 1) {
        s  += __shfl_down(s, off);
        s2 += __shfl_down(s2, off);
    }
    __shared__ float red_s[4], red_s2[4];
    const int wid = tid >> 6, lane = tid & 63;
    if (lane == 0) { red_s[wid] = s; red_s2[wid] = s2; }
    __syncthreads();
    __shared__ float sh_mean, sh_rstd;
    if (tid == 0) {
        const float ts  = red_s[0] + red_s[1] + red_s[2] + red_s[3];
        const float ts2 = red_s2[0] + red_s2[1] + red_s2[2] + red_s2[3];
        const float mean = ts * (1.f / D_DIM);
        const float var  = ts2 * (1.f / D_DIM) - mean * mean;
        sh_mean = mean;
        sh_rstd = rsqrtf(var + EPS);
    }
    __syncthreads();
    const float mean = sh_mean, rstd = sh_rstd;
#pragma unroll
    for (int i = 0; i < 3; ++i) {
        const int d = tid + i * 256;
        const float o = (vals[i] - mean) * rstd * g[d] + bb[d];
        if constexpr (sizeof(OT) == 2)
            out[(size_t)row * D_DIM + d] = (OT)f2bf(o);
        else
            out[(size_t)row * D_DIM + d] = o;
    }
}

// ---------------------------------------------------------------------------
// Launch
// ---------------------------------------------------------------------------
extern "C" void kernel_launch(void* const* d_in, const int* in_sizes, int n_in,
                              void* d_out, int out_size, void* d_ws, size_t ws_size,
                              hipStream_t stream) {
    const float* x     = (const float*)d_in[0];
    const float* wq    = (const float*)d_in[1];
    const float* bq    = (const float*)d_in[2];
    const float* wk    = (const float*)d_in[3];
    const float* bk    = (const float*)d_in[4];
    const float* wv    = (const float*)d_in[5];
    const float* bv    = (const float*)d_in[6];
    const float* wo    = (const float*)d_in[7];
    const float* bo    = (const float*)d_in[8];
    const float* ln1g  = (const float*)d_in[9];
    const float* ln1b  = (const float*)d_in[10];
    const float* w1    = (const float*)d_in[11];
    const float* b1    = (const float*)d_in[12];
    const float* w2    = (const float*)d_in[13];
    const float* b2    = (const float*)d_in[14];
    const float* ln2g  = (const float*)d_in[15];
    const float* ln2b  = (const float*)d_in[16];
    float* out = (float*)d_out;

    // workspace layout (bytes) — total 65,020,928
    char* ws = (char*)d_ws;
    short* qkvb  = (short*)(ws + 0);             // [TB,2304] bf16  0 .. 18,874,368
    short* ctxb  = (short*)(ws + 18874368);      // [TB,768]  bf16  .. 25,165,824
    short* hb    = (short*)(ws + 0);             // [TB,3072] bf16  (reuses qkvb+ctxb)
    short* xb    = (short*)(ws + 25165824);      // [TB,768]  bf16  .. 31,457,280
    short* Opart = (short*)(ws + 25165824);      // 4x[TB,768] bf16 .. 50,331,648 (over xb)
    float* lpart = (float*)(ws + 50331648);      // 4x[TB,8]  f32   .. 50,855,936
    short* tmpb  = (short*)(ws + 25165824);      // [TB,768]  bf16  (over dead Opart)
    short* x1b   = (short*)(ws + 31457280);      // [TB,768]  bf16  (over dead Opart)
    short* wqkv  = (short*)(ws + 50855936);      // [2304,768] bf16 .. 54,394,880
    short* wob   = (short*)(ws + 54394880);      // [768,768]  bf16 .. 55,574,528
    short* w1b   = (short*)(ws + 55574528);      // [3072,768] bf16 .. 60,293,120
    short* w2b   = (short*)(ws + 60293120);      // [768,3072] bf16 .. 65,011,712
    float* bqkv  = (float*)(ws + 65011712);      // [2304] f32      .. 65,020,928

    // fused fp32->bf16 conversions (wq pre-scaled by scale*log2e)
    CvtArgs ca;
    ca.src[0] = x;  ca.dst[0] = xb;   ca.scl[0] = 1.f;
    ca.src[1] = wq; ca.dst[1] = wqkv; ca.scl[1] = SC_LOG2E;
    ca.src[2] = wk; ca.dst[2] = wqkv + 768 * 768;     ca.scl[2] = 1.f;
    ca.src[3] = wv; ca.dst[3] = wqkv + 2 * 768 * 768; ca.scl[3] = 1.f;
    ca.src[4] = wo; ca.dst[4] = wob;  ca.scl[4] = 1.f;
    ca.src[5] = w1; ca.dst[5] = w1b;  ca.scl[5] = 1.f;
    ca.src[6] = w2; ca.dst[6] = w2b;  ca.scl[6] = 1.f;
    const int n4[7] = {TB * D_DIM / 4, 768 * 768 / 4, 768 * 768 / 4, 768 * 768 / 4,
                       768 * 768 / 4, FFN * 768 / 4, 768 * FFN / 4};
    int acc4 = 0;
    for (int i = 0; i < 7; ++i) { acc4 += n4[i]; ca.end4[i] = acc4; }
    cvt_all<<<(acc4 + 255) / 256, 256, 0, stream>>>(ca, acc4);
    concat_bias<<<(QKV_LD + 255) / 256, 256, 0, stream>>>(bq, bk, bv, bqkv);

    // fused QKV projection: [TB,2304] = xb @ wqkv^T + bqkv
    gemm_mfma<128, 128, 32, short, false><<<dim3(QKV_LD / 128, TB / 128), 256, 0, stream>>>(
        xb, wqkv, bqkv, qkvb, TB, QKV_LD, D_DIM);

    // attention (v5: 4-wave blocks, split-K x4, bare-v_exp softmax) + combine
    attn_mfma<<<dim3(T_LEN / 128, B_SZ * H_NUM, NSPLIT), dim3(256), 0, stream>>>(
        qkvb, Opart, lpart);
    attn_combine<<<dim3(TB), 256, 0, stream>>>(Opart, lpart, ctxb);

    // out projection: BM=64/BK=64 -> 768 blocks, 12 pipelined steps
    gemm_mfma<64, 64, 64, short, false><<<dim3(D_DIM / 64, TB / 64), 256, 0, stream>>>(
        ctxb, wob, bo, tmpb, TB, D_DIM, D_DIM);
    ln_residual<float, short><<<dim3(TB), 256, 0, stream>>>(x, tmpb, ln1g, ln1b, x1b);

    // FFN1
    gemm_mfma<128, 128, 32, short, true><<<dim3(FFN / 128, TB / 128), 256, 0, stream>>>(
        x1b, w1b, b1, hb, TB, FFN, D_DIM);
    // FFN2: BM=64/BK=64 -> 768 blocks, 48 pipelined steps (was 96 drained)
    gemm_mfma<64, 64, 64, short, false><<<dim3(D_DIM / 64, TB / 64), 256, 0, stream>>>(
        hb, w2b, b2, tmpb, TB, D_DIM, FFN);
    ln_residual<short, float><<<dim3(TB), 256, 0, stream>>>(x1b, tmpb, ln2g, ln2b, out);
}

// Round 6
// 299.102 us; speedup vs baseline: 1.1798x; 1.0030x over previous
//
#include <hip/hip_runtime.h>
#include <hip/hip_bf16.h>
#include <math.h>

// Problem constants (fixed by the reference)
constexpr int T_LEN = 2048;
constexpr int B_SZ  = 2;
constexpr int D_DIM = 768;
constexpr int H_NUM = 8;
constexpr int HD    = 96;        // D/H
constexpr int FFN   = 3072;
constexpr float EPS = 1e-5f;
constexpr int TB    = T_LEN * B_SZ;   // 4096 rows
constexpr int QKV_LD = 3 * D_DIM;     // 2304
constexpr int NSPLIT = 4;             // attention split-K factor
constexpr int CHUNK  = T_LEN / NSPLIT;   // 512 keys per block
// (1/sqrt(96)) * log2(e): folded into wq/bq so softmax is a bare v_exp (2^x)
constexpr float SC_LOG2E = 0.14724444458547f;

typedef __attribute__((ext_vector_type(8)))  short short8;
typedef __attribute__((ext_vector_type(4)))  short short4v;
typedef __attribute__((ext_vector_type(2)))  short short2v;
typedef __attribute__((ext_vector_type(4)))  float f32x4;
typedef __attribute__((ext_vector_type(16))) float f32x16;
typedef __attribute__((ext_vector_type(2)))  int   int2v;

__device__ __forceinline__ short f2bf(float f) {
    union { float f; unsigned u; } v; v.f = f;
    return (short)((v.u + 0x7FFFu + ((v.u >> 16) & 1u)) >> 16);   // RNE
}
__device__ __forceinline__ float bf2f(short s) {
    union { unsigned u; float f; } v;
    v.u = ((unsigned)(unsigned short)s) << 16;
    return v.f;
}
// packed f32x2 -> bf16x2 (V_CVT_PK_BF16_F32 on gfx950); a in low half
__device__ __forceinline__ unsigned pkbf(float a, float b) {
    union { __hip_bfloat162 h; unsigned u; } v;
    v.h = __float22bfloat162_rn(make_float2(a, b));
    return v.u;
}
__device__ __forceinline__ short4v pk4(float a, float b, float c, float d) {
    union { unsigned u[2]; short4v s; } v;
    v.u[0] = pkbf(a, b); v.u[1] = pkbf(c, d);
    return v.s;
}
__device__ __forceinline__ short8 mk8(int a, int b, int c, int d) {
    union { int u[4]; short8 s; } v;
    v.u[0] = a; v.u[1] = b; v.u[2] = c; v.u[3] = d;
    return v.s;
}

// async global->LDS, 16B per lane; LDS dst = wave-uniform base + lane*16
__device__ __forceinline__ void async_ld16(const short* g, short* l) {
    __builtin_amdgcn_global_load_lds(
        (const __attribute__((address_space(1))) unsigned int*)g,
        (__attribute__((address_space(3))) unsigned int*)l, 16, 0, 0);
}

// ---------------------------------------------------------------------------
// Prep: fused fp32 -> bf16 conversion over 7 segments (x + 6 weight blobs),
// with a per-segment scale (wq is pre-scaled by SC_LOG2E so attention's
// softmax exp becomes a bare v_exp_f32).
// ---------------------------------------------------------------------------
struct CvtArgs {
    const float* src[7];
    short*       dst[7];
    float        scl[7];
    int          end4[7];   // cumulative segment ends, in float4 units
};

__global__ __launch_bounds__(256)
void cvt_all(CvtArgs a, int total4) {
    const int i = blockIdx.x * 256 + threadIdx.x;
    if (i >= total4) return;
    int s = 0;
    while (i >= a.end4[s]) ++s;
    const int base = s ? a.end4[s - 1] : 0;
    const int j = i - base;
    const float sc = a.scl[s];
    const float4 v = ((const float4*)a.src[s])[j];
    short4v o;
    o[0] = f2bf(v.x * sc); o[1] = f2bf(v.y * sc);
    o[2] = f2bf(v.z * sc); o[3] = f2bf(v.w * sc);
    *(short4v*)(a.dst[s] + (size_t)j * 4) = o;
}

__global__ __launch_bounds__(256)
void concat_bias(const float* __restrict__ bq, const float* __restrict__ bk,
                 const float* __restrict__ bv, float* __restrict__ dst) {
    const int i = blockIdx.x * 256 + threadIdx.x;
    if (i >= QKV_LD) return;
    dst[i] = (i < 768) ? bq[i] * SC_LOG2E : (i < 1536 ? bk[i - 768] : bv[i - 1536]);
}

// ---------------------------------------------------------------------------
// bf16 MFMA GEMM: C[M,N] = A[M,K] @ W[N,K]^T + bias[N]  (optional ReLU)
// R5 (kept): counted-vmcnt 2-phase pipeline (T3+T4 minimum). Raw s_barrier +
// s_waitcnt vmcnt(4): tile t+1's 4 glds stay in flight across tile t's MFMA.
// ---------------------------------------------------------------------------
template <int BM, int BN, int BK, typename OutT, bool RELU>
__global__ __launch_bounds__(256)
void gemm_mfma(const short* __restrict__ A, const short* __restrict__ W,
               const float* __restrict__ bias, OutT* __restrict__ C,
               int M, int N, int K) {
    constexpr int MI = BM / 32;   // 16-row tiles per wave
    constexpr int NI = BN / 32;   // 16-col tiles per wave
    constexpr int KI = BK / 32;   // k-substeps per tile
    static_assert(BM * BK == 4096 && BN * BK == 4096, "4 glds/thread/stage");
    constexpr int ROWSTEP = 2048 / BK;   // rows per 2048-short call chunk
    __shared__ __align__(16) short As[2][4096];
    __shared__ __align__(16) short Bs[2][4096];

    const int tid  = threadIdx.x;
    const int w    = tid >> 6;
    const int lane = tid & 63;
    const int l16  = lane & 15;
    const int q4   = lane >> 4;          // 0..3
    const int row0 = blockIdx.y * BM;
    const int col0 = blockIdx.x * BN;
    const int wm   = (w >> 1) * (BM / 2); // wave m-offset in tile
    const int wn   = (w & 1) * (BN / 2);  // wave n-offset in tile

    // staging: thread covers shorts [c*2048 + tid*8, +8) of each 4096 tile
    const int mA = tid / (BK / 8);
    const int kA = (tid % (BK / 8)) * 8;
    const short* gA0 = A + (size_t)(row0 + mA) * K + kA;
    const short* gA1 = gA0 + (size_t)ROWSTEP * K;
    const short* gB0 = W + (size_t)(col0 + mA) * K + kA;
    const short* gB1 = gB0 + (size_t)ROWSTEP * K;

    f32x4 acc[MI][NI];
#pragma unroll
    for (int mi = 0; mi < MI; ++mi)
#pragma unroll
        for (int ni = 0; ni < NI; ++ni)
#pragma unroll
            for (int r = 0; r < 4; ++r) acc[mi][ni][r] = 0.f;

    auto stage = [&](int buf) {
        async_ld16(gA0, &As[buf][w * 512]);
        async_ld16(gA1, &As[buf][2048 + w * 512]);
        async_ld16(gB0, &Bs[buf][w * 512]);
        async_ld16(gB1, &Bs[buf][2048 + w * 512]);
        gA0 += BK; gA1 += BK; gB0 += BK; gB1 += BK;
    };
    auto compute = [&](int buf) {
#pragma unroll
        for (int ks = 0; ks < KI; ++ks) {
            short8 af[MI], bfr[NI];
#pragma unroll
            for (int mi = 0; mi < MI; ++mi)
                af[mi] = *(const short8*)&As[buf][(wm + mi * 16 + l16) * BK + ks * 32 + q4 * 8];
#pragma unroll
            for (int ni = 0; ni < NI; ++ni)
                bfr[ni] = *(const short8*)&Bs[buf][(wn + ni * 16 + l16) * BK + ks * 32 + q4 * 8];
#pragma unroll
            for (int mi = 0; mi < MI; ++mi)
#pragma unroll
                for (int ni = 0; ni < NI; ++ni)
                    acc[mi][ni] = __builtin_amdgcn_mfma_f32_16x16x32_bf16(
                        af[mi], bfr[ni], acc[mi][ni], 0, 0, 0);
        }
    };

    stage(0);                            // prologue: tile 0 in flight
    const int NT = K / BK;
    for (int t = 0; t < NT; ++t) {
        const int cur = t & 1;
        if (t + 1 < NT) {
            stage(cur ^ 1);              // 4 more glds -> 8 outstanding
            asm volatile("s_waitcnt vmcnt(4)" ::: "memory");  // oldest 4 (tile t) done
        } else {
            asm volatile("s_waitcnt vmcnt(0)" ::: "memory");  // final drain
        }
        __builtin_amdgcn_s_barrier();    // all waves: buf[cur] fully written
        __builtin_amdgcn_sched_barrier(0);
        compute(cur);
        __builtin_amdgcn_s_barrier();    // all waves: buf[cur] fully read
        __builtin_amdgcn_sched_barrier(0);
    }

    float bcol[NI];
#pragma unroll
    for (int ni = 0; ni < NI; ++ni) bcol[ni] = bias[col0 + wn + ni * 16 + l16];
#pragma unroll
    for (int mi = 0; mi < MI; ++mi) {
#pragma unroll
        for (int r = 0; r < 4; ++r) {
            const int row = row0 + wm + mi * 16 + q4 * 4 + r;
#pragma unroll
            for (int ni = 0; ni < NI; ++ni) {
                float v = acc[mi][ni][r] + bcol[ni];
                if (RELU) v = fmaxf(v, 0.f);
                const int col = col0 + wn + ni * 16 + l16;
                if constexpr (sizeof(OutT) == 2)
                    C[(size_t)row * N + col] = (OutT)f2bf(v);
                else
                    C[(size_t)row * N + col] = v;
            }
        }
    }
}

// ---------------------------------------------------------------------------
// MFMA bf16 flash attention v6: TRANSPOSED PV, in-register P (T12 pattern).
// R6: swapped QK -- S^T = mfma(K_frag, Q_frag) uses the SAME register
// contents as before (K rows as A, Q rows as B); each lane then holds
// P[q=l31][key=(r&3)+8*(r>>2)+4*h5]. PV computed transposed:
// O^T = mfma(V^T_frag, P^T_frag): Vt[d][key] already matches the A-layout;
// the P^T B-fragment is built fully in-register with 8 v_cvt_pk_bf16_f32 +
// 4 permlane32_swap (exchanges the key-halves living in lane l <-> l+32).
// This DELETES the Pw LDS round-trip (16 ds_write_b16 + 4 ds_read_b64 +
// lgkm waits per iteration) that sat on the serial QK->softmax->PV chain.
// Denominator now summed in-register (f32) -> PV is 6 MFMA (was 8), the
// Vt ones-rows are gone (Vt[96][44]), LDS 27.6 -> 15.6 KB.
// s_setprio(1) wraps both MFMA clusters (T5).
// ---------------------------------------------------------------------------
__global__ __launch_bounds__(256)
void attn_mfma(const short* __restrict__ qkv, short* __restrict__ Opart,
               float* __restrict__ lpart) {
    __shared__ short Ks[2][32][56];  // [d-half][key][d%48] bf16, conflict-free
    __shared__ short Vt[96][44];     // [d][key] bf16, stride 44

    const int tid  = threadIdx.x;
    const int w    = tid >> 6;
    const int lane = tid & 63;
    const int l31  = lane & 31;
    const int h5   = lane >> 5;
    const int t0   = blockIdx.x * 128;
    const int bh   = blockIdx.y;
    const int split = blockIdx.z;
    const int b    = bh >> 3;
    const int h    = bh & 7;

    // Q fragments straight from global bf16 (wave-private 32 q-rows)
    short8 qf[6];
    {
        const int qrow = t0 + w * 32 + l31;
        const short* qb = qkv + ((size_t)qrow * B_SZ + b) * QKV_LD + h * HD;
#pragma unroll
        for (int ks = 0; ks < 6; ++ks)
            qf[ks] = *(const short8*)&qb[ks * 16 + h5 * 8];
    }

    // --- staging assignments (wave-specialized), chunk-local keys ---
    // waves 0,1 (tid 0..127): K. 32 keys x 4 quarters of 24 d each.
    const int k_row = tid >> 2;                   // 0..31 (valid for tid<128)
    const int k_q   = tid & 3;                    // d-quarter
    const short* gK = qkv + ((size_t)(split * CHUNK + k_row) * B_SZ + b) * QKV_LD
                      + D_DIM + h * HD + k_q * 24;
    // waves 2,3 (ll = tid-128, 0..127): V. 8 d-groups x 16 key-pairs.
    const int ll = tid - 128;
    const int dg = (ll & 7) * 12;                 // d-group
    const int kg = (ll >> 3) * 2;                 // key pair
    const short* gV = qkv + ((size_t)(split * CHUNK + kg) * B_SZ + b) * QKV_LD
                      + 2 * D_DIM + h * HD + dg;
    const size_t step  = (size_t)32 * B_SZ * QKV_LD;
    const size_t vrow  = (size_t)B_SZ * QKV_LD;   // one key row

    f32x16 oacc[3];
#pragma unroll
    for (int nt = 0; nt < 3; ++nt)
#pragma unroll
        for (int r = 0; r < 16; ++r) oacc[nt][r] = 0.f;
    float dsum = 0.f;

    // prefetch tile 0 (wave-specialized, registers)
    short8  kpf[3];
    short4v vpf[2][3];
    if (w < 2) {
#pragma unroll
        for (int j = 0; j < 3; ++j) kpf[j] = *(const short8*)(gK + j * 8);
    } else {
#pragma unroll
        for (int r = 0; r < 2; ++r)
#pragma unroll
            for (int c = 0; c < 3; ++c)
                vpf[r][c] = *(const short4v*)(gV + r * vrow + c * 4);
    }

    for (int it = 0; it < CHUNK / 32; ++it) {
        __syncthreads();   // previous tile fully consumed by all waves
        if (w < 2) {
#pragma unroll
            for (int j = 0; j < 3; ++j)
                *(short8*)&Ks[k_q >> 1][k_row][(k_q & 1) * 24 + j * 8] = kpf[j];
        } else {
#pragma unroll
            for (int d = 0; d < 12; ++d) {
                short2v t;
                t[0] = vpf[0][d >> 2][d & 3];
                t[1] = vpf[1][d >> 2][d & 3];
                *(short2v*)&Vt[dg + d][kg] = t;
            }
        }
        __syncthreads();

        // prefetch next tile (latency hides behind this tile's compute)
        if (it + 1 < CHUNK / 32) {
            const size_t off = (size_t)(it + 1) * step;
            if (w < 2) {
#pragma unroll
                for (int j = 0; j < 3; ++j)
                    kpf[j] = *(const short8*)(gK + off + j * 8);
            } else {
#pragma unroll
                for (int r = 0; r < 2; ++r)
#pragma unroll
                    for (int c = 0; c < 3; ++c)
                        vpf[r][c] = *(const short4v*)(gV + off + r * vrow + c * 4);
            }
        }

        // S^T = K.Q^T (swapped operands; Q pre-scaled by scale*log2e).
        // sa[r] = S[q=l31][key=(r&3)+8*(r>>2)+4*h5]
        f32x16 sa;
#pragma unroll
        for (int r = 0; r < 16; ++r) sa[r] = 0.f;
        __builtin_amdgcn_s_setprio(1);
#pragma unroll
        for (int ks = 0; ks < 6; ++ks) {
            const int half = ks / 3;                   // compile-time per ks
            const int base = ks * 16 - half * 48;      // local d within half
            const short8 kf = *(const short8*)&Ks[half][l31][base + h5 * 8];
            sa = __builtin_amdgcn_mfma_f32_32x32x16_bf16(kf, qf[ks], sa, 0, 0, 0);
        }
        __builtin_amdgcn_s_setprio(0);

        // P = 2^S (bare v_exp), fully in-register
        float pvx[16];
#pragma unroll
        for (int r = 0; r < 16; ++r) pvx[r] = __builtin_amdgcn_exp2f(sa[r]);
        // denominator partial (this lane's 16 keys of the tile)
        dsum += ((pvx[0] + pvx[1]) + (pvx[2] + pvx[3]))
              + ((pvx[4] + pvx[5]) + (pvx[6] + pvx[7]))
              + ((pvx[8] + pvx[9]) + (pvx[10] + pvx[11]))
              + ((pvx[12] + pvx[13]) + (pvx[14] + pvx[15]));

        // pack to bf16 + permlane32_swap -> P^T B-fragments (keys 0..15, 16..31)
        int wA0 = (int)pkbf(pvx[0],  pvx[1]);
        int wA1 = (int)pkbf(pvx[2],  pvx[3]);
        int wA2 = (int)pkbf(pvx[4],  pvx[5]);
        int wA3 = (int)pkbf(pvx[6],  pvx[7]);
        int wB0 = (int)pkbf(pvx[8],  pvx[9]);
        int wB1 = (int)pkbf(pvx[10], pvx[11]);
        int wB2 = (int)pkbf(pvx[12], pvx[13]);
        int wB3 = (int)pkbf(pvx[14], pvx[15]);
        const int2v s0 = __builtin_amdgcn_permlane32_swap(wA0, wA2, false, false);
        const int2v s1 = __builtin_amdgcn_permlane32_swap(wA1, wA3, false, false);
        const int2v s2 = __builtin_amdgcn_permlane32_swap(wB0, wB2, false, false);
        const int2v s3 = __builtin_amdgcn_permlane32_swap(wB1, wB3, false, false);
        const short8 pf0 = mk8(s0[0], s1[0], s0[1], s1[1]);  // keys 0..15
        const short8 pf1 = mk8(s2[0], s3[0], s2[1], s3[1]);  // keys 16..31

        // O^T += V^T . P^T  (3 d-tiles of 32)
        __builtin_amdgcn_s_setprio(1);
#pragma unroll
        for (int ks2 = 0; ks2 < 2; ++ks2) {
            const short8 pfr = ks2 ? pf1 : pf0;
#pragma unroll
            for (int nt = 0; nt < 3; ++nt) {
                const short* vp = &Vt[nt * 32 + l31][ks2 * 16 + h5 * 8];
                const short4v vlo = *(const short4v*)vp;
                const short4v vhi = *(const short4v*)(vp + 4);
                const short8 vf = __builtin_shufflevector(vlo, vhi, 0, 1, 2, 3, 4, 5, 6, 7);
                oacc[nt] = __builtin_amdgcn_mfma_f32_32x32x16_bf16(vf, pfr, oacc[nt], 0, 0, 0);
            }
        }
        __builtin_amdgcn_s_setprio(0);
    }

    // epilogue: lane l31 = q-row; oacc[nt][r] = O^T[d=nt*32+(r&3)+8*(r>>2)+4*h5][q]
    const float other = __shfl_xor(dsum, 32);
    const float denom = dsum + other;
    const int qrow = t0 + w * 32 + l31;
    const int grow = qrow * B_SZ + b;
    short* op = Opart + ((size_t)split * TB + grow) * D_DIM + h * HD;
#pragma unroll
    for (int nt = 0; nt < 3; ++nt)
#pragma unroll
        for (int g = 0; g < 4; ++g)
            *(short4v*)&op[nt * 32 + g * 8 + h5 * 4] =
                pk4(oacc[nt][4 * g], oacc[nt][4 * g + 1],
                    oacc[nt][4 * g + 2], oacc[nt][4 * g + 3]);
    if (lane < 32)
        lpart[((size_t)split * TB + grow) * H_NUM + h] = denom;
}

// ---------------------------------------------------------------------------
// Combine: ctx = (sum_c Opart[c]) / (sum_c lpart[c]).  One block per row,
// 192 active lanes x 4 d each, short4 vector loads.
// ---------------------------------------------------------------------------
__global__ __launch_bounds__(256)
void attn_combine(const short* __restrict__ Opart, const float* __restrict__ lpart,
                  short* __restrict__ ctx) {
    const int row = blockIdx.x;
    const int tid = threadIdx.x;
    if (tid >= 192) return;
    const int d = tid * 4;
    const int h = d / 96;
    float o0 = 0.f, o1 = 0.f, o2 = 0.f, o3 = 0.f, l = 0.f;
#pragma unroll
    for (int c = 0; c < NSPLIT; ++c) {
        const short4v v = *(const short4v*)&Opart[((size_t)c * TB + row) * D_DIM + d];
        o0 += bf2f(v[0]); o1 += bf2f(v[1]); o2 += bf2f(v[2]); o3 += bf2f(v[3]);
        l += lpart[((size_t)c * TB + row) * H_NUM + h];
    }
    const float iv = 1.f / l;
    short4v r;
    r[0] = f2bf(o0 * iv); r[1] = f2bf(o1 * iv);
    r[2] = f2bf(o2 * iv); r[3] = f2bf(o3 * iv);
    *(short4v*)&ctx[(size_t)row * D_DIM + d] = r;
}

// ---------------------------------------------------------------------------
// Fused residual + LayerNorm: out = LN(xres + y)*g + b.  (unchanged)
// ---------------------------------------------------------------------------
template <typename XT, typename OT>
__global__ __launch_bounds__(256)
void ln_residual(const XT* __restrict__ xres, const short* __restrict__ y,
                 const float* __restrict__ g, const float* __restrict__ bb,
                 OT* __restrict__ out) {
    const int row = blockIdx.x;
    const int tid = threadIdx.x;
    const XT*    xr = xres + (size_t)row * D_DIM;
    const short* yr = y + (size_t)row * D_DIM;

    float vals[3];
    float s = 0.f, s2 = 0.f;
#pragma unroll
    for (int i = 0; i < 3; ++i) {
        const int d = tid + i * 256;
        float xv;
        if constexpr (sizeof(XT) == 2) xv = bf2f((short)xr[d]);
        else                           xv = (float)xr[d];
        const float t = xv + bf2f(yr[d]);
        vals[i] = t;
        s += t;
        s2 = fmaf(t, t, s2);
    }
#pragma unroll
    for (int off = 32; off > 0; off >>= 1) {
        s  += __shfl_down(s, off);
        s2 += __shfl_down(s2, off);
    }
    __shared__ float red_s[4], red_s2[4];
    const int wid = tid >> 6, lane = tid & 63;
    if (lane == 0) { red_s[wid] = s; red_s2[wid] = s2; }
    __syncthreads();
    __shared__ float sh_mean, sh_rstd;
    if (tid == 0) {
        const float ts  = red_s[0] + red_s[1] + red_s[2] + red_s[3];
        const float ts2 = red_s2[0] + red_s2[1] + red_s2[2] + red_s2[3];
        const float mean = ts * (1.f / D_DIM);
        const float var  = ts2 * (1.f / D_DIM) - mean * mean;
        sh_mean = mean;
        sh_rstd = rsqrtf(var + EPS);
    }
    __syncthreads();
    const float mean = sh_mean, rstd = sh_rstd;
#pragma unroll
    for (int i = 0; i < 3; ++i) {
        const int d = tid + i * 256;
        const float o = (vals[i] - mean) * rstd * g[d] + bb[d];
        if constexpr (sizeof(OT) == 2)
            out[(size_t)row * D_DIM + d] = (OT)f2bf(o);
        else
            out[(size_t)row * D_DIM + d] = o;
    }
}

// ---------------------------------------------------------------------------
// Launch
// ---------------------------------------------------------------------------
extern "C" void kernel_launch(void* const* d_in, const int* in_sizes, int n_in,
                              void* d_out, int out_size, void* d_ws, size_t ws_size,
                              hipStream_t stream) {
    const float* x     = (const float*)d_in[0];
    const float* wq    = (const float*)d_in[1];
    const float* bq    = (const float*)d_in[2];
    const float* wk    = (const float*)d_in[3];
    const float* bk    = (const float*)d_in[4];
    const float* wv    = (const float*)d_in[5];
    const float* bv    = (const float*)d_in[6];
    const float* wo    = (const float*)d_in[7];
    const float* bo    = (const float*)d_in[8];
    const float* ln1g  = (const float*)d_in[9];
    const float* ln1b  = (const float*)d_in[10];
    const float* w1    = (const float*)d_in[11];
    const float* b1    = (const float*)d_in[12];
    const float* w2    = (const float*)d_in[13];
    const float* b2    = (const float*)d_in[14];
    const float* ln2g  = (const float*)d_in[15];
    const float* ln2b  = (const float*)d_in[16];
    float* out = (float*)d_out;

    // workspace layout (bytes) — total 65,020,928
    char* ws = (char*)d_ws;
    short* qkvb  = (short*)(ws + 0);             // [TB,2304] bf16  0 .. 18,874,368
    short* ctxb  = (short*)(ws + 18874368);      // [TB,768]  bf16  .. 25,165,824
    short* hb    = (short*)(ws + 0);             // [TB,3072] bf16  (reuses qkvb+ctxb)
    short* xb    = (short*)(ws + 25165824);      // [TB,768]  bf16  .. 31,457,280
    short* Opart = (short*)(ws + 25165824);      // 4x[TB,768] bf16 .. 50,331,648 (over xb)
    float* lpart = (float*)(ws + 50331648);      // 4x[TB,8]  f32   .. 50,855,936
    short* tmpb  = (short*)(ws + 25165824);      // [TB,768]  bf16  (over dead Opart)
    short* x1b   = (short*)(ws + 31457280);      // [TB,768]  bf16  (over dead Opart)
    short* wqkv  = (short*)(ws + 50855936);      // [2304,768] bf16 .. 54,394,880
    short* wob   = (short*)(ws + 54394880);      // [768,768]  bf16 .. 55,574,528
    short* w1b   = (short*)(ws + 55574528);      // [3072,768] bf16 .. 60,293,120
    short* w2b   = (short*)(ws + 60293120);      // [768,3072] bf16 .. 65,011,712
    float* bqkv  = (float*)(ws + 65011712);      // [2304] f32      .. 65,020,928

    // fused fp32->bf16 conversions (wq pre-scaled by scale*log2e)
    CvtArgs ca;
    ca.src[0] = x;  ca.dst[0] = xb;   ca.scl[0] = 1.f;
    ca.src[1] = wq; ca.dst[1] = wqkv; ca.scl[1] = SC_LOG2E;
    ca.src[2] = wk; ca.dst[2] = wqkv + 768 * 768;     ca.scl[2] = 1.f;
    ca.src[3] = wv; ca.dst[3] = wqkv + 2 * 768 * 768; ca.scl[3] = 1.f;
    ca.src[4] = wo; ca.dst[4] = wob;  ca.scl[4] = 1.f;
    ca.src[5] = w1; ca.dst[5] = w1b;  ca.scl[5] = 1.f;
    ca.src[6] = w2; ca.dst[6] = w2b;  ca.scl[6] = 1.f;
    const int n4[7] = {TB * D_DIM / 4, 768 * 768 / 4, 768 * 768 / 4, 768 * 768 / 4,
                       768 * 768 / 4, FFN * 768 / 4, 768 * FFN / 4};
    int acc4 = 0;
    for (int i = 0; i < 7; ++i) { acc4 += n4[i]; ca.end4[i] = acc4; }
    cvt_all<<<(acc4 + 255) / 256, 256, 0, stream>>>(ca, acc4);
    concat_bias<<<(QKV_LD + 255) / 256, 256, 0, stream>>>(bq, bk, bv, bqkv);

    // fused QKV projection: [TB,2304] = xb @ wqkv^T + bqkv
    gemm_mfma<128, 128, 32, short, false><<<dim3(QKV_LD / 128, TB / 128), 256, 0, stream>>>(
        xb, wqkv, bqkv, qkvb, TB, QKV_LD, D_DIM);

    // attention (v6: transposed PV, in-register P, setprio) + combine
    attn_mfma<<<dim3(T_LEN / 128, B_SZ * H_NUM, NSPLIT), dim3(256), 0, stream>>>(
        qkvb, Opart, lpart);
    attn_combine<<<dim3(TB), 256, 0, stream>>>(Opart, lpart, ctxb);

    // out projection: BM=64/BK=64 -> 768 blocks, 12 pipelined steps
    gemm_mfma<64, 64, 64, short, false><<<dim3(D_DIM / 64, TB / 64), 256, 0, stream>>>(
        ctxb, wob, bo, tmpb, TB, D_DIM, D_DIM);
    ln_residual<float, short><<<dim3(TB), 256, 0, stream>>>(x, tmpb, ln1g, ln1b, x1b);

    // FFN1
    gemm_mfma<128, 128, 32, short, true><<<dim3(FFN / 128, TB / 128), 256, 0, stream>>>(
        x1b, w1b, b1, hb, TB, FFN, D_DIM);
    // FFN2: BM=64/BK=64 -> 768 blocks, 48 pipelined steps
    gemm_mfma<64, 64, 64, short, false><<<dim3(D_DIM / 64, TB / 64), 256, 0, stream>>>(
        hb, w2b, b2, tmpb, TB, D_DIM, FFN);
    ln_residual<short, float><<<dim3(TB), 256, 0, stream>>>(x1b, tmpb, ln2g, ln2b, out);
}